// Round 1
// baseline (1798.174 us; speedup 1.0000x reference)
//
#include <hip/hip_runtime.h>
#include <math.h>

#define BB 4096
#define SS 10
#define EE 1536
#define HH 12
#define HDIM 128
#define MROWS (BB * SS)   // 40960 rows per branch

typedef short short8 __attribute__((ext_vector_type(8)));
typedef float f32x4 __attribute__((ext_vector_type(4)));
typedef const unsigned char __attribute__((address_space(1))) gu8;
typedef unsigned char __attribute__((address_space(3))) lu8;

__device__ __forceinline__ unsigned short f2bf(float x) {
  unsigned int u = __float_as_uint(x);
  return (unsigned short)((u + 0x7FFFu + ((u >> 16) & 1u)) >> 16);
}
__device__ __forceinline__ float bf2f(unsigned short u) {
  return __uint_as_float(((unsigned int)u) << 16);
}

// ---- mask dtype detection (bool bytes vs int32 vs f32) ---------------------
// Safe region: first BB*SS bytes exist under every interpretation.
// bool: padding '1' bytes land at j%4==1 (rows with even b, len<=9) -> flag 1
// f32 : 1.0f = 00 00 80 3f -> nonzero at j%4==2/3 (never j%4==1)    -> flag 2
// int32: nonzero only at j%4==0                                      -> flag 0
__global__ void k_detect(const unsigned char* __restrict__ m, int* __restrict__ flag) {
  __shared__ int fb, ff;
  if (threadIdx.x == 0) { fb = 0; ff = 0; }
  __syncthreads();
  int lb = 0, lf = 0;
  for (int j = threadIdx.x; j < BB * SS; j += blockDim.x) {
    unsigned char v = m[j];
    if (v) {
      int r = j & 3;
      if (r == 1) lb = 1;
      else if (r >= 2) lf = 1;
    }
  }
  if (lb) atomicOr(&fb, 1);
  if (lf) atomicOr(&ff, 1);
  __syncthreads();
  if (threadIdx.x == 0) *flag = fb ? 1 : (ff ? 2 : 0);
}

__global__ void k_lastidx(const void* __restrict__ ma, const void* __restrict__ mb,
                          const int* __restrict__ flag, int* __restrict__ lastidx) {
  int idx = blockIdx.x * blockDim.x + threadIdx.x;
  if (idx >= 2 * BB) return;
  const void* m = (idx >= BB) ? mb : ma;
  int b = idx & (BB - 1);
  int f = *flag;
  int len = 0;
  for (int s = 0; s < SS; ++s) {
    int j = b * SS + s;
    int pad;
    if (f == 1)      pad = ((const unsigned char*)m)[j] != 0;
    else if (f == 2) pad = ((const float*)m)[j] != 0.0f;
    else             pad = ((const int*)m)[j] != 0;
    len += (pad == 0);
  }
  lastidx[idx] = len - 1;
}

// ---- positional-encoding table --------------------------------------------
__global__ void k_pe(float* __restrict__ pe) {
  int idx = blockIdx.x * blockDim.x + threadIdx.x;
  if (idx >= SS * EE) return;
  int s = idx / EE, e = idx - (idx / EE) * EE;
  float fe = (float)(e & ~1);
  float freq = expf(fe * (-9.210340371976184f / (float)EE));  // -ln(10000)/E
  float arg = (float)s * freq;
  pe[idx] = (e & 1) ? cosf(arg) : sinf(arg);
}

// ---- weight transpose f32[K][N] -> bf16[N][K] ------------------------------
__global__ void k_trans(const float* __restrict__ w0, const float* __restrict__ w1,
                        const float* __restrict__ w2, const float* __restrict__ w3,
                        const float* __restrict__ w4, unsigned short* __restrict__ wt) {
  __shared__ float tile[32][33];
  int z = blockIdx.z;
  const float* W = z == 0 ? w0 : z == 1 ? w1 : z == 2 ? w2 : z == 3 ? w3 : w4;
  unsigned short* T = wt + (size_t)z * EE * EE;
  int n0 = blockIdx.x * 32, k0 = blockIdx.y * 32;
  int tx = threadIdx.x, ty = threadIdx.y;
#pragma unroll
  for (int i = 0; i < 4; ++i)
    tile[ty + i * 8][tx] = W[(size_t)(k0 + ty + i * 8) * EE + n0 + tx];
  __syncthreads();
#pragma unroll
  for (int i = 0; i < 4; ++i)
    T[(size_t)(n0 + ty + i * 8) * EE + k0 + tx] = f2bf(tile[tx][ty + i * 8]);
}

// ---- fused add-PE + LayerNorm (two-pass, f32) -> bf16 + last-row gather ----
__global__ __launch_bounds__(256) void k_ln(
    const float* __restrict__ xin, const float* __restrict__ pe,
    const float* __restrict__ g, const float* __restrict__ be,
    const int* __restrict__ lastidx,
    unsigned short* __restrict__ xln, unsigned short* __restrict__ lastx) {
  __shared__ float red[4];
  int row = blockIdx.x;                  // 0..MROWS-1 (this branch)
  int b = row / SS, s = row - b * SS;
  const float2* x2 = (const float2*)(xin + (size_t)row * EE);
  const float2* p2 = (const float2*)(pe + s * EE);
  int t = threadIdx.x;
  float2 v[3];
  float lsum = 0.f;
#pragma unroll
  for (int i = 0; i < 3; ++i) {
    int e2 = t + i * 256;
    float2 a = x2[e2], p = p2[e2];
    a.x += p.x; a.y += p.y;
    v[i] = a;
    lsum += a.x + a.y;
  }
  for (int off = 32; off; off >>= 1) lsum += __shfl_xor(lsum, off, 64);
  if ((t & 63) == 0) red[t >> 6] = lsum;
  __syncthreads();
  float mu = (red[0] + red[1] + red[2] + red[3]) * (1.0f / EE);
  __syncthreads();
  float lss = 0.f;
#pragma unroll
  for (int i = 0; i < 3; ++i) {
    float dx = v[i].x - mu, dy = v[i].y - mu;
    lss += dx * dx + dy * dy;
  }
  for (int off = 32; off; off >>= 1) lss += __shfl_xor(lss, off, 64);
  if ((t & 63) == 0) red[t >> 6] = lss;
  __syncthreads();
  float var = (red[0] + red[1] + red[2] + red[3]) * (1.0f / EE);
  float scl = rsqrtf(var + 1e-5f);
  bool isLast = (s == lastidx[b]);
  unsigned int* orow = (unsigned int*)(xln + (size_t)row * EE);
  unsigned int* lrow = (unsigned int*)(lastx + (size_t)b * EE);
  const float2* g2 = (const float2*)g;
  const float2* b2 = (const float2*)be;
#pragma unroll
  for (int i = 0; i < 3; ++i) {
    int e2 = t + i * 256;
    float2 gg = g2[e2], bb = b2[e2];
    float ox = (v[i].x - mu) * scl * gg.x + bb.x;
    float oy = (v[i].y - mu) * scl * gg.y + bb.y;
    unsigned int pk = (unsigned int)f2bf(ox) | ((unsigned int)f2bf(oy) << 16);
    orow[e2] = pk;
    if (isLast) lrow[e2] = pk;
  }
}

// ---- m97-structure bf16 GEMM: C[M][N] = A[M][K] @ Bt[N][K]^T + bias --------
// 128x128 tile, 4 waves (2x2), 16x16x32 MFMA, global_load_lds width-16,
// XCD-swizzled n-fastest ordering (requires (M/128)%8==0, K%32==0, N%128==0).
// EPI 0: store bf16.  EPI 2: bias+exact GELU, store f32.
template<int EPI>
__global__ __launch_bounds__(256) void k_gemm(
    const unsigned short* __restrict__ A, const unsigned short* __restrict__ Bt,
    const float* __restrict__ bias1, const float* __restrict__ bias2, int nsplit,
    void* __restrict__ C, int M, int N, int K) {
  __shared__ __align__(16) unsigned char smA[8192];
  __shared__ __align__(16) unsigned char smB[8192];
  const int Ntiles = N >> 7;
  const int per = (M >> 7) >> 3;
  int bid = blockIdx.x;
  int xcd = bid & 7, lin = bid >> 3;
  int mt = xcd * per + lin / Ntiles;
  int nt = lin % Ntiles;
  int m0 = mt << 7, n0 = nt << 7;
  int tid = threadIdx.x, wid = tid >> 6, lane = tid & 63;
  int wm = wid >> 1, wn = wid & 1;
  f32x4 acc[4][4] = {};
  const int ldb = K * 2;  // row bytes
  const unsigned char* Ab = (const unsigned char*)A;
  const unsigned char* Bb = (const unsigned char*)Bt;
  int lrow = lane & 15, kgrp = lane >> 4;
  int aoff = (wm * 64 + lrow) * 64 + kgrp * 16;
  int boff = (wn * 64 + lrow) * 64 + kgrp * 16;
  int Lbase = wid * 1024 + lane * 16;
  const int nk = K >> 5;
  for (int kt = 0; kt < nk; ++kt) {
    int k0b = kt << 6;
#pragma unroll
    for (int issue = 0; issue < 2; ++issue) {
      int L = issue * 4096 + Lbase;
      int row = L >> 6, colb = L & 63;
      int Lu = issue * 4096 + wid * 1024;  // wave-uniform LDS base; HW adds lane*16
      __builtin_amdgcn_global_load_lds((gu8*)(Ab + (size_t)(m0 + row) * ldb + k0b + colb),
                                       (lu8*)(smA + Lu), 16, 0, 0);
      __builtin_amdgcn_global_load_lds((gu8*)(Bb + (size_t)(n0 + row) * ldb + k0b + colb),
                                       (lu8*)(smB + Lu), 16, 0, 0);
    }
    __syncthreads();
    short8 af[4], bfr[4];
#pragma unroll
    for (int i = 0; i < 4; ++i) {
      af[i]  = *(const short8*)(smA + aoff + i * 1024);
      bfr[i] = *(const short8*)(smB + boff + i * 1024);
    }
#pragma unroll
    for (int mi = 0; mi < 4; ++mi)
#pragma unroll
      for (int ni = 0; ni < 4; ++ni)
        acc[mi][ni] = __builtin_amdgcn_mfma_f32_16x16x32_bf16(af[mi], bfr[ni], acc[mi][ni], 0, 0, 0);
    __syncthreads();
  }
  int rbase = m0 + wm * 64 + (lane >> 4) * 4;
  int cbase = n0 + wn * 64 + (lane & 15);
#pragma unroll
  for (int mi = 0; mi < 4; ++mi) {
#pragma unroll
    for (int ni = 0; ni < 4; ++ni) {
      int c = cbase + ni * 16;
      float bv = (c < nsplit) ? bias1[c] : bias2[c - nsplit];
#pragma unroll
      for (int j = 0; j < 4; ++j) {
        int r = rbase + mi * 16 + j;
        float val = acc[mi][ni][j] + bv;
        if (EPI == 2) {
          val = 0.5f * val * (1.0f + erff(val * 0.7071067811865476f));
          ((float*)C)[(size_t)r * N + c] = val;
        } else {
          ((unsigned short*)C)[(size_t)r * N + c] = f2bf(val);
        }
      }
    }
  }
}

// ---- attention over S=10 with single query row per batch -------------------
__global__ __launch_bounds__(256) void k_attn(
    const unsigned short* __restrict__ q,   // [BB][EE]
    const unsigned short* __restrict__ kv,  // [MROWS][2*EE] : k | v per row
    const int* __restrict__ lastidx,        // [BB]
    unsigned short* __restrict__ ctx) {     // [BB][EE]
  __shared__ float qs[EE];
  __shared__ float wsm[HH][SS];
  int b = blockIdx.x;
  int t = threadIdx.x;
  int li = lastidx[b];
  const unsigned short* qr = q + (size_t)b * EE;
  for (int e = t; e < EE; e += 256) qs[e] = bf2f(qr[e]);
  __syncthreads();
  if (t < HH * SS) {
    int h = t / SS, s = t - (t / SS) * SS;
    float sc = -1e9f;
    if (s <= li) {
      const short8* k8 = (const short8*)(kv + ((size_t)b * SS + s) * (2 * EE) + h * HDIM);
      const float* qh = qs + h * HDIM;
      float d = 0.f;
#pragma unroll
      for (int i = 0; i < HDIM / 8; ++i) {
        short8 kk = k8[i];
#pragma unroll
        for (int j = 0; j < 8; ++j) d += qh[i * 8 + j] * bf2f((unsigned short)kk[j]);
      }
      sc = d * 0.08838834764831845f;   // HD^-0.5
    }
    wsm[h][s] = sc;
  }
  __syncthreads();
  if (t < HH) {
    float mx = -1e30f;
#pragma unroll
    for (int s = 0; s < SS; ++s) mx = fmaxf(mx, wsm[t][s]);
    float ex[SS]; float sum = 0.f;
#pragma unroll
    for (int s = 0; s < SS; ++s) { ex[s] = expf(wsm[t][s] - mx); sum += ex[s]; }
    float inv = 1.0f / sum;
#pragma unroll
    for (int s = 0; s < SS; ++s) wsm[t][s] = ex[s] * inv;
  }
  __syncthreads();
  for (int e = t; e < EE; e += 256) {
    int h = e >> 7;
    float a = 0.f;
    for (int s = 0; s <= li; ++s)
      a += wsm[h][s] * bf2f(kv[((size_t)b * SS + s) * (2 * EE) + EE + e]);
    ctx[(size_t)b * EE + e] = f2bf(a);
  }
}

extern "C" void kernel_launch(void* const* d_in, const int* in_sizes, int n_in,
                              void* d_out, int out_size, void* d_ws, size_t ws_size,
                              hipStream_t stream) {
  (void)in_sizes; (void)n_in; (void)out_size; (void)ws_size;
  const float* av  = (const float*)d_in[0];
  const float* bv  = (const float*)d_in[1];
  const void*  ma  = d_in[2];
  const void*  mb  = d_in[3];
  const float* qw  = (const float*)d_in[4];
  const float* qb  = (const float*)d_in[5];
  const float* kw  = (const float*)d_in[6];
  const float* kb  = (const float*)d_in[7];
  const float* vw  = (const float*)d_in[8];
  const float* vbs = (const float*)d_in[9];
  const float* ow  = (const float*)d_in[10];
  const float* ob  = (const float*)d_in[11];
  const float* fw  = (const float*)d_in[12];
  const float* fbs = (const float*)d_in[13];
  const float* lng = (const float*)d_in[14];
  const float* lnb = (const float*)d_in[15];

  unsigned char* ws = (unsigned char*)d_ws;
  size_t off = 0;
  auto alloc = [&](size_t bytes) {
    size_t r = off; off = (off + bytes + 255) & ~(size_t)255; return (void*)(ws + r);
  };
  int* flag             = (int*)alloc(4);
  float* pe             = (float*)alloc((size_t)SS * EE * 4);
  unsigned short* wt    = (unsigned short*)alloc((size_t)5 * EE * EE * 2);
  int* lastidx          = (int*)alloc((size_t)2 * BB * 4);
  unsigned short* xln   = (unsigned short*)alloc((size_t)MROWS * EE * 2);   // 126 MB
  unsigned short* lastx = (unsigned short*)alloc((size_t)BB * EE * 2);
  unsigned short* qbuf  = (unsigned short*)alloc((size_t)BB * EE * 2);
  unsigned short* kvp   = (unsigned short*)alloc((size_t)MROWS * 2 * EE * 2); // 252 MB
  unsigned short* ctx   = (unsigned short*)alloc((size_t)BB * EE * 2);
  unsigned short* o1    = (unsigned short*)alloc((size_t)BB * EE * 2);

  k_detect<<<1, 256, 0, stream>>>((const unsigned char*)ma, flag);
  k_pe<<<(SS * EE + 255) / 256, 256, 0, stream>>>(pe);
  k_trans<<<dim3(EE / 32, EE / 32, 5), dim3(32, 8), 0, stream>>>(qw, kw, vw, ow, fw, wt);
  k_lastidx<<<(2 * BB + 255) / 256, 256, 0, stream>>>(ma, mb, flag, lastidx);

  for (int br = 0; br < 2; ++br) {
    const float* xin = br ? bv : av;
    const int* li = lastidx + br * BB;
    k_ln<<<MROWS, 256, 0, stream>>>(xin, pe, lng, lnb, li, xln, lastx);
    // Q projection on gathered last rows: [4096 x 1536] @ qw
    k_gemm<0><<<(BB / 128) * (EE / 128), 256, 0, stream>>>(
        lastx, wt, qb, qb, EE, qbuf, BB, EE, EE);
    // fused K|V projection: [40960 x 1536] @ [kt ; vt] -> [40960 x 3072]
    k_gemm<0><<<(MROWS / 128) * (2 * EE / 128), 256, 0, stream>>>(
        xln, wt + (size_t)EE * EE, kb, vbs, EE, kvp, MROWS, 2 * EE, EE);
    k_attn<<<BB, 256, 0, stream>>>(qbuf, kvp, li, ctx);
    // O projection
    k_gemm<0><<<(BB / 128) * (EE / 128), 256, 0, stream>>>(
        ctx, wt + (size_t)3 * EE * EE, ob, ob, EE, o1, BB, EE, EE);
    // F projection + exact GELU -> f32 output (branch-major = concat order)
    k_gemm<2><<<(BB / 128) * (EE / 128), 256, 0, stream>>>(
        o1, wt + (size_t)4 * EE * EE, fbs, fbs, EE,
        (float*)d_out + (size_t)br * BB * EE, BB, EE, EE);
  }
}

// Round 2
// 1324.113 us; speedup vs baseline: 1.3580x; 1.3580x over previous
//
#include <hip/hip_runtime.h>
#include <math.h>

#define BB 4096
#define SS 10
#define EE 1536
#define HH 12
#define HDIM 128
#define MROWS (BB * SS)   // 40960 rows per branch

typedef short short8 __attribute__((ext_vector_type(8)));
typedef float f32x4 __attribute__((ext_vector_type(4)));
typedef const unsigned char __attribute__((address_space(1))) gu8;
typedef unsigned char __attribute__((address_space(3))) lu8;

__device__ __forceinline__ unsigned short f2bf(float x) {
  unsigned int u = __float_as_uint(x);
  return (unsigned short)((u + 0x7FFFu + ((u >> 16) & 1u)) >> 16);
}
__device__ __forceinline__ float bf2f(unsigned short u) {
  return __uint_as_float(((unsigned int)u) << 16);
}

// ---- mask dtype detection (bool bytes vs int32 vs f32) ---------------------
__global__ void k_detect(const unsigned char* __restrict__ m, int* __restrict__ flag) {
  __shared__ int fb, ff;
  if (threadIdx.x == 0) { fb = 0; ff = 0; }
  __syncthreads();
  int lb = 0, lf = 0;
  for (int j = threadIdx.x; j < BB * SS; j += blockDim.x) {
    unsigned char v = m[j];
    if (v) {
      int r = j & 3;
      if (r == 1) lb = 1;
      else if (r >= 2) lf = 1;
    }
  }
  if (lb) atomicOr(&fb, 1);
  if (lf) atomicOr(&ff, 1);
  __syncthreads();
  if (threadIdx.x == 0) *flag = fb ? 1 : (ff ? 2 : 0);
}

__global__ void k_lastidx(const void* __restrict__ ma, const void* __restrict__ mb,
                          const int* __restrict__ flag, int* __restrict__ lastidx) {
  int idx = blockIdx.x * blockDim.x + threadIdx.x;
  if (idx >= 2 * BB) return;
  const void* m = (idx >= BB) ? mb : ma;
  int b = idx & (BB - 1);
  int f = *flag;
  int len = 0;
  for (int s = 0; s < SS; ++s) {
    int j = b * SS + s;
    int pad;
    if (f == 1)      pad = ((const unsigned char*)m)[j] != 0;
    else if (f == 2) pad = ((const float*)m)[j] != 0.0f;
    else             pad = ((const int*)m)[j] != 0;
    len += (pad == 0);
  }
  lastidx[idx] = len - 1;
}

// ---- positional-encoding table --------------------------------------------
__global__ void k_pe(float* __restrict__ pe) {
  int idx = blockIdx.x * blockDim.x + threadIdx.x;
  if (idx >= SS * EE) return;
  int s = idx / EE, e = idx - (idx / EE) * EE;
  float fe = (float)(e & ~1);
  float freq = expf(fe * (-9.210340371976184f / (float)EE));  // -ln(10000)/E
  float arg = (float)s * freq;
  pe[idx] = (e & 1) ? cosf(arg) : sinf(arg);
}

// ---- weight transpose f32[K][N] -> bf16[N][K] ------------------------------
__global__ void k_trans(const float* __restrict__ w0, const float* __restrict__ w1,
                        const float* __restrict__ w2, const float* __restrict__ w3,
                        const float* __restrict__ w4, unsigned short* __restrict__ wt) {
  __shared__ float tile[32][33];
  int z = blockIdx.z;
  const float* W = z == 0 ? w0 : z == 1 ? w1 : z == 2 ? w2 : z == 3 ? w3 : w4;
  unsigned short* T = wt + (size_t)z * EE * EE;
  int n0 = blockIdx.x * 32, k0 = blockIdx.y * 32;
  int tx = threadIdx.x, ty = threadIdx.y;
#pragma unroll
  for (int i = 0; i < 4; ++i)
    tile[ty + i * 8][tx] = W[(size_t)(k0 + ty + i * 8) * EE + n0 + tx];
  __syncthreads();
#pragma unroll
  for (int i = 0; i < 4; ++i)
    T[(size_t)(n0 + ty + i * 8) * EE + k0 + tx] = f2bf(tile[tx][ty + i * 8]);
}

// ---- fused add-PE + LayerNorm (two-pass, f32) -> bf16 + last-row gather ----
__global__ __launch_bounds__(256) void k_ln(
    const float* __restrict__ xin, const float* __restrict__ pe,
    const float* __restrict__ g, const float* __restrict__ be,
    const int* __restrict__ lastidx,
    unsigned short* __restrict__ xln, unsigned short* __restrict__ lastx) {
  __shared__ float red[4];
  int row = blockIdx.x;
  int b = row / SS, s = row - b * SS;
  const float2* x2 = (const float2*)(xin + (size_t)row * EE);
  const float2* p2 = (const float2*)(pe + s * EE);
  int t = threadIdx.x;
  float2 v[3];
  float lsum = 0.f;
#pragma unroll
  for (int i = 0; i < 3; ++i) {
    int e2 = t + i * 256;
    float2 a = x2[e2], p = p2[e2];
    a.x += p.x; a.y += p.y;
    v[i] = a;
    lsum += a.x + a.y;
  }
  for (int off = 32; off; off >>= 1) lsum += __shfl_xor(lsum, off, 64);
  if ((t & 63) == 0) red[t >> 6] = lsum;
  __syncthreads();
  float mu = (red[0] + red[1] + red[2] + red[3]) * (1.0f / EE);
  __syncthreads();
  float lss = 0.f;
#pragma unroll
  for (int i = 0; i < 3; ++i) {
    float dx = v[i].x - mu, dy = v[i].y - mu;
    lss += dx * dx + dy * dy;
  }
  for (int off = 32; off; off >>= 1) lss += __shfl_xor(lss, off, 64);
  if ((t & 63) == 0) red[t >> 6] = lss;
  __syncthreads();
  float var = (red[0] + red[1] + red[2] + red[3]) * (1.0f / EE);
  float scl = rsqrtf(var + 1e-5f);
  bool isLast = (s == lastidx[b]);
  unsigned int* orow = (unsigned int*)(xln + (size_t)row * EE);
  unsigned int* lrow = (unsigned int*)(lastx + (size_t)b * EE);
  const float2* g2 = (const float2*)g;
  const float2* b2 = (const float2*)be;
#pragma unroll
  for (int i = 0; i < 3; ++i) {
    int e2 = t + i * 256;
    float2 gg = g2[e2], bb = b2[e2];
    float ox = (v[i].x - mu) * scl * gg.x + bb.x;
    float oy = (v[i].y - mu) * scl * gg.y + bb.y;
    unsigned int pk = (unsigned int)f2bf(ox) | ((unsigned int)f2bf(oy) << 16);
    orow[e2] = pk;
    if (isLast) lrow[e2] = pk;
  }
}

// ---- 128x128 m97-structure bf16 GEMM (kept for M=4096/8192 projections) ----
template<int EPI>
__global__ __launch_bounds__(256) void k_gemm(
    const unsigned short* __restrict__ A, const unsigned short* __restrict__ Bt,
    const float* __restrict__ bias1, const float* __restrict__ bias2, int nsplit,
    void* __restrict__ C, int M, int N, int K) {
  __shared__ __align__(16) unsigned char smA[8192];
  __shared__ __align__(16) unsigned char smB[8192];
  const int Ntiles = N >> 7;
  const int per = (M >> 7) >> 3;
  int bid = blockIdx.x;
  int xcd = bid & 7, lin = bid >> 3;
  int mt = xcd * per + lin / Ntiles;
  int nt = lin % Ntiles;
  int m0 = mt << 7, n0 = nt << 7;
  int tid = threadIdx.x, wid = tid >> 6, lane = tid & 63;
  int wm = wid >> 1, wn = wid & 1;
  f32x4 acc[4][4] = {};
  const int ldb = K * 2;
  const unsigned char* Ab = (const unsigned char*)A;
  const unsigned char* Bb = (const unsigned char*)Bt;
  int lrow = lane & 15, kgrp = lane >> 4;
  int aoff = (wm * 64 + lrow) * 64 + kgrp * 16;
  int boff = (wn * 64 + lrow) * 64 + kgrp * 16;
  int Lbase = wid * 1024 + lane * 16;
  const int nk = K >> 5;
  for (int kt = 0; kt < nk; ++kt) {
    int k0b = kt << 6;
#pragma unroll
    for (int issue = 0; issue < 2; ++issue) {
      int L = issue * 4096 + Lbase;
      int row = L >> 6, colb = L & 63;
      int Lu = issue * 4096 + wid * 1024;
      __builtin_amdgcn_global_load_lds((gu8*)(Ab + (size_t)(m0 + row) * ldb + k0b + colb),
                                       (lu8*)(smA + Lu), 16, 0, 0);
      __builtin_amdgcn_global_load_lds((gu8*)(Bb + (size_t)(n0 + row) * ldb + k0b + colb),
                                       (lu8*)(smB + Lu), 16, 0, 0);
    }
    __syncthreads();
    short8 af[4], bfr[4];
#pragma unroll
    for (int i = 0; i < 4; ++i) {
      af[i]  = *(const short8*)(smA + aoff + i * 1024);
      bfr[i] = *(const short8*)(smB + boff + i * 1024);
    }
#pragma unroll
    for (int mi = 0; mi < 4; ++mi)
#pragma unroll
      for (int ni = 0; ni < 4; ++ni)
        acc[mi][ni] = __builtin_amdgcn_mfma_f32_16x16x32_bf16(af[mi], bfr[ni], acc[mi][ni], 0, 0, 0);
    __syncthreads();
  }
  int rbase = m0 + wm * 64 + (lane >> 4) * 4;
  int cbase = n0 + wn * 64 + (lane & 15);
#pragma unroll
  for (int mi = 0; mi < 4; ++mi) {
#pragma unroll
    for (int ni = 0; ni < 4; ++ni) {
      int c = cbase + ni * 16;
      float bv = (c < nsplit) ? bias1[c] : bias2[c - nsplit];
#pragma unroll
      for (int j = 0; j < 4; ++j) {
        int r = rbase + mi * 16 + j;
        float val = acc[mi][ni][j] + bv;
        if (EPI == 2) {
          val = 0.5f * val * (1.0f + erff(val * 0.7071067811865476f));
          ((float*)C)[(size_t)r * N + c] = val;
        } else {
          ((unsigned short*)C)[(size_t)r * N + c] = f2bf(val);
        }
      }
    }
  }
}

// ---- 256x256 8-phase bf16 GEMM (T1+T2+T3+T4+T5) ----------------------------
// BM=BN=256, BK=64, 8 waves (2Mx4N), wave tile 128x64, frag 16x16x32.
// LDS 128 KiB: buf{0,1} x (A [256][128B] + B [256][128B]).
// 16B-slot swizzle: phys slot = logical slot ^ (row&7); applied on the
// per-lane GLOBAL source address (global_load_lds dest stays linear) and on
// the ds_read address. Requires (M/256)%8==0, (M/256/8)%4==0, N%256==0, K%128==0.
#define MMAQ(AR_, BR_, QM, QN)                                                  \
  do {                                                                          \
    _Pragma("unroll")                                                           \
    for (int mi_ = 0; mi_ < 4; ++mi_) {                                         \
      _Pragma("unroll")                                                         \
      for (int ni_ = 0; ni_ < 2; ++ni_) {                                       \
        acc[(QM)*4 + mi_][(QN)*2 + ni_] = __builtin_amdgcn_mfma_f32_16x16x32_bf16( \
            AR_[mi_][0], BR_[ni_][0], acc[(QM)*4 + mi_][(QN)*2 + ni_], 0, 0, 0);   \
        acc[(QM)*4 + mi_][(QN)*2 + ni_] = __builtin_amdgcn_mfma_f32_16x16x32_bf16( \
            AR_[mi_][1], BR_[ni_][1], acc[(QM)*4 + mi_][(QN)*2 + ni_], 0, 0, 0);   \
      }                                                                         \
    }                                                                           \
  } while (0)

#define PHASE_MID()                                      \
  do {                                                   \
    __builtin_amdgcn_s_barrier();                        \
    asm volatile("s_waitcnt lgkmcnt(0)" ::: "memory");   \
    __builtin_amdgcn_s_setprio(1);                       \
  } while (0)
#define PHASE_END()                                      \
  do {                                                   \
    __builtin_amdgcn_s_setprio(0);                       \
    __builtin_amdgcn_s_barrier();                        \
  } while (0)

__global__ __launch_bounds__(512, 2) void k_gemm256(
    const unsigned short* __restrict__ A, const unsigned short* __restrict__ Bt,
    const float* __restrict__ bias1, const float* __restrict__ bias2, int nsplit,
    unsigned short* __restrict__ C, int M, int N, int K) {
  __shared__ __align__(16) unsigned char lds[131072];
  const int NT = K >> 6;
  const int niters = NT >> 1;
  const int Ntiles = N >> 8;
  const int perx = (M >> 8) >> 3;
  const int MTG = 4;
  int bid = blockIdx.x;
  int xcd = bid & 7, lin = bid >> 3;
  int grp = lin / (MTG * Ntiles);
  int rem = lin - grp * (MTG * Ntiles);
  int nt = rem / MTG, mi_ = rem - nt * MTG;
  int mt = xcd * perx + grp * MTG + mi_;
  int m0 = mt << 8, n0 = nt << 8;
  int tid = threadIdx.x;
  int w = tid >> 6, lane = tid & 63;
  int wm = w >> 2, wn = w & 3;
  const size_t lda = (size_t)K * 2;
  const unsigned char* Ag = (const unsigned char*)A;
  const unsigned char* Bg = (const unsigned char*)Bt;

  unsigned char* A0 = lds;
  unsigned char* B0 = lds + 32768;
  unsigned char* A1 = lds + 65536;
  unsigned char* B1 = lds + 98304;

  // staging geometry (per lane)
  int lrows = lane >> 3;                     // row-within-8 block selector
  int colswz = (((lane & 7) ^ (lrows & 7)) << 4);
  int rowA = w * 8;                          // + q*64 + i*128
  int rowB = (w >> 2) * 64 + (w & 3) * 8;    // + q*32 + i*128

  auto stageA = [&](unsigned char* ldsA, int q, int kt) {
    int cb = kt * 128 + colswz;
#pragma unroll
    for (int i = 0; i < 2; ++i) {
      int tr = q * 64 + i * 128 + rowA;
      __builtin_amdgcn_global_load_lds(
          (gu8*)(Ag + (size_t)(m0 + tr + lrows) * lda + cb),
          (lu8*)(ldsA + tr * 128), 16, 0, 0);
    }
  };
  auto stageB = [&](unsigned char* ldsB, int q, int kt) {
    int cb = kt * 128 + colswz;
#pragma unroll
    for (int i = 0; i < 2; ++i) {
      int tr = q * 32 + i * 128 + rowB;
      __builtin_amdgcn_global_load_lds(
          (gu8*)(Bg + (size_t)(n0 + tr + lrows) * lda + cb),
          (lu8*)(ldsB + tr * 128), 16, 0, 0);
    }
  };

  // ds_read geometry (per lane)
  int lrow = lane & 15, kgrp = lane >> 4, r7 = lane & 7;
  int s0 = ((kgrp ^ r7) << 4), s1 = (((kgrp | 4) ^ r7) << 4);
  int abase = (wm * 128 + lrow) * 128;
  int bbase = (wn * 64 + lrow) * 128;

  short8 ar[4][2], br0[2][2], br1[2][2];
  f32x4 acc[8][4];
#pragma unroll
  for (int i = 0; i < 8; ++i)
#pragma unroll
    for (int j = 0; j < 4; ++j) acc[i][j] = (f32x4)0.f;

  auto ldA = [&](unsigned char* ldsA, int qm) {
#pragma unroll
    for (int mi2 = 0; mi2 < 4; ++mi2) {
      ar[mi2][0] = *(const short8*)(ldsA + abase + qm * 8192 + mi2 * 2048 + s0);
      ar[mi2][1] = *(const short8*)(ldsA + abase + qm * 8192 + mi2 * 2048 + s1);
    }
  };
  auto ldB = [&](unsigned char* ldsB, int qn, short8 (&br)[2][2]) {
#pragma unroll
    for (int ni2 = 0; ni2 < 2; ++ni2) {
      br[ni2][0] = *(const short8*)(ldsB + bbase + qn * 4096 + ni2 * 2048 + s0);
      br[ni2][1] = *(const short8*)(ldsB + bbase + qn * 4096 + ni2 * 2048 + s1);
    }
  };

  // prologue: buf0 <- tile0 {Aq0,Bq0,Aq1,Bq1}; buf1 <- tile1 {Aq0,Bq0}
  stageA(A0, 0, 0); stageB(B0, 0, 0); stageA(A0, 1, 0); stageB(B0, 1, 0);
  stageA(A1, 0, 1); stageB(B1, 0, 1);
  asm volatile("s_waitcnt vmcnt(8)" ::: "memory");
  __builtin_amdgcn_s_barrier();

  for (int it = 0; it < niters - 1; ++it) {
    int t1 = 2 * it + 1, t2 = 2 * it + 2, t3 = 2 * it + 3;
    // p0: compute buf0 (qm0,qn0); stage buf1.Aq1(t1)
    ldA(A0, 0); ldB(B0, 0, br0);
    stageA(A1, 1, t1);
    asm volatile("s_waitcnt vmcnt(6)" ::: "memory");
    PHASE_MID(); MMAQ(ar, br0, 0, 0); PHASE_END();
    // p1: (qm0,qn1); stage buf1.Bq1(t1)
    ldB(B0, 1, br1);
    stageB(B1, 1, t1);
    PHASE_MID(); MMAQ(ar, br1, 0, 1); PHASE_END();
    // p2: (qm1,qn0); stage buf0.Aq0(t2)
    ldA(A0, 1);
    stageA(A0, 0, t2);
    PHASE_MID(); MMAQ(ar, br0, 1, 0); PHASE_END();
    // p3: (qm1,qn1); stage buf0.Bq0(t2)
    stageB(B0, 0, t2);
    asm volatile("s_waitcnt vmcnt(8)" ::: "memory");
    PHASE_MID(); MMAQ(ar, br1, 1, 1); PHASE_END();
    // p4: compute buf1 (qm0,qn0); stage buf0.Aq1(t2)
    ldA(A1, 0); ldB(B1, 0, br0);
    stageA(A0, 1, t2);
    asm volatile("s_waitcnt vmcnt(6)" ::: "memory");
    PHASE_MID(); MMAQ(ar, br0, 0, 0); PHASE_END();
    // p5: (qm0,qn1); stage buf0.Bq1(t2)
    ldB(B1, 1, br1);
    stageB(B0, 1, t2);
    PHASE_MID(); MMAQ(ar, br1, 0, 1); PHASE_END();
    // p6: (qm1,qn0); stage buf1.Aq0(t3)
    ldA(A1, 1);
    if (t3 < NT) stageA(A1, 0, t3);
    PHASE_MID(); MMAQ(ar, br0, 1, 0); PHASE_END();
    // p7: (qm1,qn1); stage buf1.Bq0(t3)
    if (t3 < NT) stageB(B1, 0, t3);
    asm volatile("s_waitcnt vmcnt(8)" ::: "memory");
    PHASE_MID(); MMAQ(ar, br1, 1, 1); PHASE_END();
  }
  {
    // peeled last iter: no t2/t3 stages; guards tightened accordingly
    int t1 = NT - 1;
    ldA(A0, 0); ldB(B0, 0, br0);
    stageA(A1, 1, t1);
    asm volatile("s_waitcnt vmcnt(6)" ::: "memory");
    PHASE_MID(); MMAQ(ar, br0, 0, 0); PHASE_END();
    ldB(B0, 1, br1);
    stageB(B1, 1, t1);
    PHASE_MID(); MMAQ(ar, br1, 0, 1); PHASE_END();
    ldA(A0, 1);
    PHASE_MID(); MMAQ(ar, br0, 1, 0); PHASE_END();
    asm volatile("s_waitcnt vmcnt(4)" ::: "memory");
    PHASE_MID(); MMAQ(ar, br1, 1, 1); PHASE_END();
    ldA(A1, 0); ldB(B1, 0, br0);
    asm volatile("s_waitcnt vmcnt(2)" ::: "memory");
    PHASE_MID(); MMAQ(ar, br0, 0, 0); PHASE_END();
    ldB(B1, 1, br1);
    asm volatile("s_waitcnt vmcnt(0)" ::: "memory");
    PHASE_MID(); MMAQ(ar, br1, 0, 1); PHASE_END();
    ldA(A1, 1);
    PHASE_MID(); MMAQ(ar, br0, 1, 0); PHASE_END();
    PHASE_MID(); MMAQ(ar, br1, 1, 1); PHASE_END();
  }

  int rb = m0 + wm * 128 + (lane >> 4) * 4;
  int cb2 = n0 + wn * 64 + (lane & 15);
#pragma unroll
  for (int fm = 0; fm < 8; ++fm)
#pragma unroll
    for (int fn = 0; fn < 4; ++fn) {
      int c = cb2 + fn * 16;
      float bv = (c < nsplit) ? bias1[c] : bias2[c - nsplit];
#pragma unroll
      for (int j = 0; j < 4; ++j) {
        int r = rb + fm * 16 + j;
        C[(size_t)r * N + c] = f2bf(acc[fm][fn][j] + bv);
      }
    }
}

// ---- attention over S=10 with single query row per batch -------------------
__global__ __launch_bounds__(256) void k_attn(
    const unsigned short* __restrict__ q,
    const unsigned short* __restrict__ kv,
    const int* __restrict__ lastidx,
    unsigned short* __restrict__ ctx) {
  __shared__ float qs[EE];
  __shared__ float wsm[HH][SS];
  int b = blockIdx.x;
  int t = threadIdx.x;
  int li = lastidx[b];
  const unsigned short* qr = q + (size_t)b * EE;
  for (int e = t; e < EE; e += 256) qs[e] = bf2f(qr[e]);
  __syncthreads();
  if (t < HH * SS) {
    int h = t / SS, s = t - (t / SS) * SS;
    float sc = -1e9f;
    if (s <= li) {
      const short8* k8 = (const short8*)(kv + ((size_t)b * SS + s) * (2 * EE) + h * HDIM);
      const float* qh = qs + h * HDIM;
      float d = 0.f;
#pragma unroll
      for (int i = 0; i < HDIM / 8; ++i) {
        short8 kk = k8[i];
#pragma unroll
        for (int j = 0; j < 8; ++j) d += qh[i * 8 + j] * bf2f((unsigned short)kk[j]);
      }
      sc = d * 0.08838834764831845f;
    }
    wsm[h][s] = sc;
  }
  __syncthreads();
  if (t < HH) {
    float mx = -1e30f;
#pragma unroll
    for (int s = 0; s < SS; ++s) mx = fmaxf(mx, wsm[t][s]);
    float ex[SS]; float sum = 0.f;
#pragma unroll
    for (int s = 0; s < SS; ++s) { ex[s] = expf(wsm[t][s] - mx); sum += ex[s]; }
    float inv = 1.0f / sum;
#pragma unroll
    for (int s = 0; s < SS; ++s) wsm[t][s] = ex[s] * inv;
  }
  __syncthreads();
  for (int e = t; e < EE; e += 256) {
    int h = e >> 7;
    float a = 0.f;
    for (int s = 0; s <= li; ++s)
      a += wsm[h][s] * bf2f(kv[((size_t)b * SS + s) * (2 * EE) + EE + e]);
    ctx[(size_t)b * EE + e] = f2bf(a);
  }
}

extern "C" void kernel_launch(void* const* d_in, const int* in_sizes, int n_in,
                              void* d_out, int out_size, void* d_ws, size_t ws_size,
                              hipStream_t stream) {
  (void)in_sizes; (void)n_in; (void)out_size; (void)ws_size;
  const float* av  = (const float*)d_in[0];
  const float* bv  = (const float*)d_in[1];
  const void*  ma  = d_in[2];
  const void*  mb  = d_in[3];
  const float* qw  = (const float*)d_in[4];
  const float* qb  = (const float*)d_in[5];
  const float* kw  = (const float*)d_in[6];
  const float* kb  = (const float*)d_in[7];
  const float* vw  = (const float*)d_in[8];
  const float* vbs = (const float*)d_in[9];
  const float* ow  = (const float*)d_in[10];
  const float* ob  = (const float*)d_in[11];
  const float* fw  = (const float*)d_in[12];
  const float* fbs = (const float*)d_in[13];
  const float* lng = (const float*)d_in[14];
  const float* lnb = (const float*)d_in[15];

  unsigned char* ws = (unsigned char*)d_ws;
  size_t off = 0;
  auto alloc = [&](size_t bytes) {
    size_t r = off; off = (off + bytes + 255) & ~(size_t)255; return (void*)(ws + r);
  };
  int* flag             = (int*)alloc(4);
  float* pe             = (float*)alloc((size_t)SS * EE * 4);
  unsigned short* wt    = (unsigned short*)alloc((size_t)5 * EE * EE * 2);
  int* lastidx          = (int*)alloc((size_t)2 * BB * 4);
  unsigned short* xln   = (unsigned short*)alloc((size_t)MROWS * EE * 2);      // 126 MB
  unsigned short* lastx = (unsigned short*)alloc((size_t)2 * BB * EE * 2);
  unsigned short* qbuf  = (unsigned short*)alloc((size_t)2 * BB * EE * 2);
  unsigned short* kvp   = (unsigned short*)alloc((size_t)MROWS * 2 * EE * 2);  // 252 MB
  unsigned short* ctx   = (unsigned short*)alloc((size_t)2 * BB * EE * 2);
  unsigned short* o1    = (unsigned short*)alloc((size_t)2 * BB * EE * 2);

  k_detect<<<1, 256, 0, stream>>>((const unsigned char*)ma, flag);
  k_pe<<<(SS * EE + 255) / 256, 256, 0, stream>>>(pe);
  k_trans<<<dim3(EE / 32, EE / 32, 5), dim3(32, 8), 0, stream>>>(qw, kw, vw, ow, fw, wt);
  k_lastidx<<<(2 * BB + 255) / 256, 256, 0, stream>>>(ma, mb, flag, lastidx);

  for (int br = 0; br < 2; ++br) {
    const float* xin = br ? bv : av;
    const int* li = lastidx + br * BB;
    k_ln<<<MROWS, 256, 0, stream>>>(xin, pe, lng, lnb, li, xln, lastx + (size_t)br * BB * EE);
    // fused K|V projection: [40960 x 1536] @ [kt ; vt] -> [40960 x 3072], 8-phase 256^2
    k_gemm256<<<(MROWS / 256) * (2 * EE / 256), 512, 0, stream>>>(
        xln, wt + (size_t)EE * EE, kb, vbs, EE, kvp, MROWS, 2 * EE, EE);
    // Q projection on gathered last rows
    k_gemm<0><<<(BB / 128) * (EE / 128), 256, 0, stream>>>(
        lastx + (size_t)br * BB * EE, wt, qb, qb, EE,
        qbuf + (size_t)br * BB * EE, BB, EE, EE);
    k_attn<<<BB, 256, 0, stream>>>(qbuf + (size_t)br * BB * EE, kvp, li,
                                   ctx + (size_t)br * BB * EE);
  }
  // batched O projection over both branches: [8192 x 1536]
  k_gemm<0><<<(2 * BB / 128) * (EE / 128), 256, 0, stream>>>(
      ctx, wt + (size_t)3 * EE * EE, ob, ob, EE, o1, 2 * BB, EE, EE);
  // batched F projection + exact GELU -> f32 output (branch-major)
  k_gemm<2><<<(2 * BB / 128) * (EE / 128), 256, 0, stream>>>(
      o1, wt + (size_t)4 * EE * EE, fbs, fbs, EE, (float*)d_out, 2 * BB, EE, EE);
}

// Round 4
// 1015.137 us; speedup vs baseline: 1.7714x; 1.3044x over previous
//
#include <hip/hip_runtime.h>
#include <math.h>

#define BB 4096
#define SS 10
#define EE 1536
#define HH 12
#define HDIM 128
#define MROWS (BB * SS)   // 40960 rows per branch

typedef short short8 __attribute__((ext_vector_type(8)));
typedef float f32x4 __attribute__((ext_vector_type(4)));
typedef const unsigned char __attribute__((address_space(1))) gu8;
typedef unsigned char __attribute__((address_space(3))) lu8;

__device__ __forceinline__ unsigned short f2bf(float x) {
  unsigned int u = __float_as_uint(x);
  return (unsigned short)((u + 0x7FFFu + ((u >> 16) & 1u)) >> 16);
}
__device__ __forceinline__ float bf2f(unsigned short u) {
  return __uint_as_float(((unsigned int)u) << 16);
}

// ---- mask dtype detection (bool bytes vs int32 vs f32) ---------------------
__global__ void k_detect(const unsigned char* __restrict__ m, int* __restrict__ flag) {
  __shared__ int fb, ff;
  if (threadIdx.x == 0) { fb = 0; ff = 0; }
  __syncthreads();
  int lb = 0, lf = 0;
  for (int j = threadIdx.x; j < BB * SS; j += blockDim.x) {
    unsigned char v = m[j];
    if (v) {
      int r = j & 3;
      if (r == 1) lb = 1;
      else if (r >= 2) lf = 1;
    }
  }
  if (lb) atomicOr(&fb, 1);
  if (lf) atomicOr(&ff, 1);
  __syncthreads();
  if (threadIdx.x == 0) *flag = fb ? 1 : (ff ? 2 : 0);
}

__global__ void k_lastidx(const void* __restrict__ ma, const void* __restrict__ mb,
                          const int* __restrict__ flag, int* __restrict__ lastidx) {
  int idx = blockIdx.x * blockDim.x + threadIdx.x;
  if (idx >= 2 * BB) return;
  const void* m = (idx >= BB) ? mb : ma;
  int b = idx & (BB - 1);
  int f = *flag;
  int len = 0;
  for (int s = 0; s < SS; ++s) {
    int j = b * SS + s;
    int pad;
    if (f == 1)      pad = ((const unsigned char*)m)[j] != 0;
    else if (f == 2) pad = ((const float*)m)[j] != 0.0f;
    else             pad = ((const int*)m)[j] != 0;
    len += (pad == 0);
  }
  lastidx[idx] = len - 1;
}

// ---- positional-encoding table --------------------------------------------
__global__ void k_pe(float* __restrict__ pe) {
  int idx = blockIdx.x * blockDim.x + threadIdx.x;
  if (idx >= SS * EE) return;
  int s = idx / EE, e = idx - (idx / EE) * EE;
  float fe = (float)(e & ~1);
  float freq = expf(fe * (-9.210340371976184f / (float)EE));  // -ln(10000)/E
  float arg = (float)s * freq;
  pe[idx] = (e & 1) ? cosf(arg) : sinf(arg);
}

// ---- weight transpose f32[K][N] -> bf16[N][K] ------------------------------
__global__ void k_trans(const float* __restrict__ w0, const float* __restrict__ w1,
                        const float* __restrict__ w2, const float* __restrict__ w3,
                        const float* __restrict__ w4, unsigned short* __restrict__ wt) {
  __shared__ float tile[32][33];
  int z = blockIdx.z;
  const float* W = z == 0 ? w0 : z == 1 ? w1 : z == 2 ? w2 : z == 3 ? w3 : w4;
  unsigned short* T = wt + (size_t)z * EE * EE;
  int n0 = blockIdx.x * 32, k0 = blockIdx.y * 32;
  int tx = threadIdx.x, ty = threadIdx.y;
#pragma unroll
  for (int i = 0; i < 4; ++i)
    tile[ty + i * 8][tx] = W[(size_t)(k0 + ty + i * 8) * EE + n0 + tx];
  __syncthreads();
#pragma unroll
  for (int i = 0; i < 4; ++i)
    T[(size_t)(n0 + ty + i * 8) * EE + k0 + tx] = f2bf(tile[tx][ty + i * 8]);
}

// ---- straight f32 -> bf16 cast (layout preserved) --------------------------
__global__ void k_cast(const float* __restrict__ in, unsigned short* __restrict__ out) {
  int i = (blockIdx.x * blockDim.x + threadIdx.x) * 8;
  if (i >= EE * EE) return;
  float4 a = *(const float4*)(in + i);
  float4 b = *(const float4*)(in + i + 4);
  short8 v;
  v[0] = (short)f2bf(a.x); v[1] = (short)f2bf(a.y);
  v[2] = (short)f2bf(a.z); v[3] = (short)f2bf(a.w);
  v[4] = (short)f2bf(b.x); v[5] = (short)f2bf(b.y);
  v[6] = (short)f2bf(b.z); v[7] = (short)f2bf(b.w);
  *(short8*)(out + i) = v;
}

// ---- fused add-PE + LayerNorm (two-pass, f32) -> bf16 + last-row gather ----
__global__ __launch_bounds__(256) void k_ln(
    const float* __restrict__ xin, const float* __restrict__ pe,
    const float* __restrict__ g, const float* __restrict__ be,
    const int* __restrict__ lastidx,
    unsigned short* __restrict__ xln, unsigned short* __restrict__ lastx) {
  __shared__ float red[4];
  int row = blockIdx.x;
  int b = row / SS, s = row - b * SS;
  const float2* x2 = (const float2*)(xin + (size_t)row * EE);
  const float2* p2 = (const float2*)(pe + s * EE);
  int t = threadIdx.x;
  float2 v[3];
  float lsum = 0.f;
#pragma unroll
  for (int i = 0; i < 3; ++i) {
    int e2 = t + i * 256;
    float2 a = x2[e2], p = p2[e2];
    a.x += p.x; a.y += p.y;
    v[i] = a;
    lsum += a.x + a.y;
  }
  for (int off = 32; off; off >>= 1) lsum += __shfl_xor(lsum, off, 64);
  if ((t & 63) == 0) red[t >> 6] = lsum;
  __syncthreads();
  float mu = (red[0] + red[1] + red[2] + red[3]) * (1.0f / EE);
  __syncthreads();
  float lss = 0.f;
#pragma unroll
  for (int i = 0; i < 3; ++i) {
    float dx = v[i].x - mu, dy = v[i].y - mu;
    lss += dx * dx + dy * dy;
  }
  for (int off = 32; off; off >>= 1) lss += __shfl_xor(lss, off, 64);
  if ((t & 63) == 0) red[t >> 6] = lss;
  __syncthreads();
  float var = (red[0] + red[1] + red[2] + red[3]) * (1.0f / EE);
  float scl = rsqrtf(var + 1e-5f);
  bool isLast = (s == lastidx[b]);
  unsigned int* orow = (unsigned int*)(xln + (size_t)row * EE);
  unsigned int* lrow = (unsigned int*)(lastx + (size_t)b * EE);
  const float2* g2 = (const float2*)g;
  const float2* b2 = (const float2*)be;
#pragma unroll
  for (int i = 0; i < 3; ++i) {
    int e2 = t + i * 256;
    float2 gg = g2[e2], bb = b2[e2];
    float ox = (v[i].x - mu) * scl * gg.x + bb.x;
    float oy = (v[i].y - mu) * scl * gg.y + bb.y;
    unsigned int pk = (unsigned int)f2bf(ox) | ((unsigned int)f2bf(oy) << 16);
    orow[e2] = pk;
    if (isLast) lrow[e2] = pk;
  }
}

// ---- generalized 128x128 m97-structure bf16 GEMM ---------------------------
// C[h-plane][m][n] = sum_k A[h][m][k] * Bt[h][n][k], per-h element offsets
// aStrH/bStrH/cStrH/biasStrH (blockIdx.y = h). EPI 0: +bias -> bf16.
// EPI 2: +bias, exact GELU -> f32. Requires MB%8==0, K%32==0.
template<int EPI>
__global__ __launch_bounds__(256) void k_gemm_g(
    const unsigned short* __restrict__ A, int aStrH, int lda,
    const unsigned short* __restrict__ Bt, int bStrH, int ldb,
    const float* __restrict__ bias, int biasStrH,
    void* __restrict__ C, int cStrH, int ldc,
    int MB, int NB, int K) {
  __shared__ __align__(16) unsigned char smA[8192];
  __shared__ __align__(16) unsigned char smB[8192];
  int h = blockIdx.y;
  const unsigned char* Ab = (const unsigned char*)(A + (size_t)h * aStrH);
  const unsigned char* Bb = (const unsigned char*)(Bt + (size_t)h * bStrH);
  const float* bi = bias ? bias + (size_t)h * biasStrH : nullptr;
  int per = MB >> 3;
  int bid = blockIdx.x;
  int xcd = bid & 7, lin = bid >> 3;
  int mt = xcd * per + lin / NB;
  int nt = lin % NB;
  int m0 = mt << 7, n0 = nt << 7;
  int tid = threadIdx.x, wid = tid >> 6, lane = tid & 63;
  int wm = wid >> 1, wn = wid & 1;
  f32x4 acc[4][4] = {};
  const size_t ldaB = (size_t)lda * 2, ldbB = (size_t)ldb * 2;
  int lrow = lane & 15, kgrp = lane >> 4;
  int aoff = (wm * 64 + lrow) * 64 + kgrp * 16;
  int boff = (wn * 64 + lrow) * 64 + kgrp * 16;
  int Lbase = wid * 1024 + lane * 16;
  const int nk = K >> 5;
  for (int kt = 0; kt < nk; ++kt) {
    int k0b = kt << 6;
#pragma unroll
    for (int issue = 0; issue < 2; ++issue) {
      int L = issue * 4096 + Lbase;
      int row = L >> 6, colb = L & 63;
      int Lu = issue * 4096 + wid * 1024;
      __builtin_amdgcn_global_load_lds((gu8*)(Ab + (size_t)(m0 + row) * ldaB + k0b + colb),
                                       (lu8*)(smA + Lu), 16, 0, 0);
      __builtin_amdgcn_global_load_lds((gu8*)(Bb + (size_t)(n0 + row) * ldbB + k0b + colb),
                                       (lu8*)(smB + Lu), 16, 0, 0);
    }
    __syncthreads();
    short8 af[4], bfr[4];
#pragma unroll
    for (int i = 0; i < 4; ++i) {
      af[i]  = *(const short8*)(smA + aoff + i * 1024);
      bfr[i] = *(const short8*)(smB + boff + i * 1024);
    }
#pragma unroll
    for (int mi = 0; mi < 4; ++mi)
#pragma unroll
      for (int ni = 0; ni < 4; ++ni)
        acc[mi][ni] = __builtin_amdgcn_mfma_f32_16x16x32_bf16(af[mi], bfr[ni], acc[mi][ni], 0, 0, 0);
    __syncthreads();
  }
  int rbase = m0 + wm * 64 + (lane >> 4) * 4;
  int cbase = n0 + wn * 64 + (lane & 15);
#pragma unroll
  for (int mi = 0; mi < 4; ++mi) {
#pragma unroll
    for (int ni = 0; ni < 4; ++ni) {
      int c = cbase + ni * 16;
      float bv = bi ? bi[c] : 0.f;
#pragma unroll
      for (int j = 0; j < 4; ++j) {
        int r = rbase + mi * 16 + j;
        float val = acc[mi][ni][j] + bv;
        if (EPI == 2) {
          val = 0.5f * val * (1.0f + erff(val * 0.7071067811865476f));
          ((float*)C)[(size_t)h * cStrH + (size_t)r * ldc + c] = val;
        } else {
          ((unsigned short*)C)[(size_t)h * cStrH + (size_t)r * ldc + c] = f2bf(val);
        }
      }
    }
  }
}

// ---- fused scores + softmax + weighted-sum ---------------------------------
// Per block b: S[h,s] = qk[b,h].x_ln[b,s] (MFMA 16x16, K=1536 split over 4
// waves), softmax over valid s, then y[b,h] = sum_s w[h,s] x_ln[b,s] (VALU
// outer product). y overwrites qk in place (block b is sole reader of qk[b]).
__global__ __launch_bounds__(256) void k_attn2(
    const unsigned short* __restrict__ xln,   // [BB*SS][EE]
    unsigned short* qky,                      // [BB][HH*EE]  in: qk, out: y
    const int* __restrict__ lastidx) {
  __shared__ __align__(16) unsigned short xs[10 * 1544];
  __shared__ __align__(16) unsigned short qs[12 * 1544];
  __shared__ float swp[4 * 256];
  __shared__ float scf[120];
  __shared__ float wsm[120];
  int b = blockIdx.x;
  int t = threadIdx.x;
  const unsigned short* xg = xln + (size_t)b * SS * EE;
  unsigned short* qg = qky + (size_t)b * HH * EE;
  // cooperative load x (10x1536) and qk (12x1536) into padded LDS
#pragma unroll
  for (int j = 0; j < 8; ++j) {
    int idx = t + j * 256;
    if (idx < 1920) {
      int row = idx / 192, col = (idx - row * 192) * 8;
      *(short8*)(xs + row * 1544 + col) = *(const short8*)(xg + row * 1536 + col);
    }
  }
#pragma unroll
  for (int j = 0; j < 9; ++j) {
    int idx = t + j * 256;
    if (idx < 2304) {
      int row = idx / 192, col = (idx - row * 192) * 8;
      *(short8*)(qs + row * 1544 + col) = *(const short8*)(qg + row * 1536 + col);
    }
  }
  __syncthreads();
  // scores: one 16x16 tile, K split across 4 waves
  int w = t >> 6, lane = t & 63;
  {
    int hr = lane & 15; if (hr > 11) hr = 11;   // A row (head), clamp
    int sr = lane & 15; if (sr > 9) sr = 9;     // B row (seq), clamp
    int kg = lane >> 4;
    f32x4 pacc = (f32x4)0.f;
#pragma unroll
    for (int kt = 0; kt < 12; ++kt) {
      int k0 = w * 384 + kt * 32 + kg * 8;
      short8 a = *(const short8*)(qs + hr * 1544 + k0);
      short8 bf = *(const short8*)(xs + sr * 1544 + k0);
      pacc = __builtin_amdgcn_mfma_f32_16x16x32_bf16(a, bf, pacc, 0, 0, 0);
    }
    int prow = (lane >> 4) * 4, pcol = lane & 15;
#pragma unroll
    for (int j = 0; j < 4; ++j)
      swp[w * 256 + (prow + j) * 16 + pcol] = pacc[j];
  }
  __syncthreads();
  if (t < 120) {
    int h = t / 10, s = t - (t / 10) * 10;
    float v = swp[h * 16 + s] + swp[256 + h * 16 + s] +
              swp[512 + h * 16 + s] + swp[768 + h * 16 + s];
    scf[t] = v * 0.08838834764831845f;  // HD^-0.5
  }
  __syncthreads();
  int li = lastidx[b];
  if (t < 12) {
    float mx = -1e30f;
    for (int s = 0; s <= li; ++s) mx = fmaxf(mx, scf[t * 10 + s]);
    float sum = 0.f;
    for (int s = 0; s <= li; ++s) {
      float e = expf(scf[t * 10 + s] - mx);
      wsm[t * 10 + s] = e; sum += e;
    }
    float inv = 1.0f / sum;
    for (int s = 0; s <= li; ++s) wsm[t * 10 + s] *= inv;
  }
  __syncthreads();
  // y phase: wave w handles heads 3w..3w+2; lane covers 2 e's per pass
  float wv[3][10];
#pragma unroll
  for (int hl = 0; hl < 3; ++hl)
#pragma unroll
    for (int s = 0; s < 10; ++s)
      wv[hl][s] = (s <= li) ? wsm[(3 * w + hl) * 10 + s] : 0.f;
#pragma unroll
  for (int pass = 0; pass < 12; ++pass) {
    int e0 = pass * 128 + lane * 2;
    float acc[3][2] = {};
    for (int s = 0; s <= li; ++s) {
      unsigned int x2 = *(const unsigned int*)(xs + s * 1544 + e0);
      float xlo = bf2f((unsigned short)(x2 & 0xffff));
      float xhi = bf2f((unsigned short)(x2 >> 16));
#pragma unroll
      for (int hl = 0; hl < 3; ++hl) {
        acc[hl][0] += wv[hl][s] * xlo;
        acc[hl][1] += wv[hl][s] * xhi;
      }
    }
#pragma unroll
    for (int hl = 0; hl < 3; ++hl) {
      unsigned int pk = (unsigned int)f2bf(acc[hl][0]) | ((unsigned int)f2bf(acc[hl][1]) << 16);
      *(unsigned int*)(qg + (3 * w + hl) * 1536 + e0) = pk;
    }
  }
}

extern "C" void kernel_launch(void* const* d_in, const int* in_sizes, int n_in,
                              void* d_out, int out_size, void* d_ws, size_t ws_size,
                              hipStream_t stream) {
  (void)in_sizes; (void)n_in; (void)out_size; (void)ws_size;
  const float* av  = (const float*)d_in[0];
  const float* bv  = (const float*)d_in[1];
  const void*  ma  = d_in[2];
  const void*  mb  = d_in[3];
  const float* qw  = (const float*)d_in[4];
  const float* qb  = (const float*)d_in[5];
  const float* kw  = (const float*)d_in[6];
  const float* kb  = (const float*)d_in[7];  (void)kb;  // softmax-invariant, dropped
  const float* vw  = (const float*)d_in[8];
  const float* vbs = (const float*)d_in[9];
  const float* ow  = (const float*)d_in[10];
  const float* ob  = (const float*)d_in[11];
  const float* fw  = (const float*)d_in[12];
  const float* fbs = (const float*)d_in[13];
  const float* lng = (const float*)d_in[14];
  const float* lnb = (const float*)d_in[15];

  unsigned char* ws = (unsigned char*)d_ws;
  size_t off = 0;
  auto alloc = [&](size_t bytes) {
    size_t r = off; off = (off + bytes + 255) & ~(size_t)255; return (void*)(ws + r);
  };
  int* flag             = (int*)alloc(4);
  float* pe             = (float*)alloc((size_t)SS * EE * 4);
  unsigned short* wt    = (unsigned short*)alloc((size_t)5 * EE * EE * 2);
  unsigned short* kwb   = (unsigned short*)alloc((size_t)EE * EE * 2);  // Wk bf16, [in][out]
  int* lastidx          = (int*)alloc((size_t)2 * BB * 4);
  unsigned short* xln   = (unsigned short*)alloc((size_t)MROWS * EE * 2);       // 126 MB
  unsigned short* lastx = (unsigned short*)alloc((size_t)BB * EE * 2);
  unsigned short* qbuf  = (unsigned short*)alloc((size_t)BB * EE * 2);
  unsigned short* qky   = (unsigned short*)alloc((size_t)BB * HH * EE * 2);     // 151 MB
  unsigned short* ctx   = (unsigned short*)alloc((size_t)2 * BB * EE * 2);
  unsigned short* o1    = (unsigned short*)alloc((size_t)2 * BB * EE * 2);

  unsigned short* wt_q = wt;
  unsigned short* wt_v = wt + (size_t)2 * EE * EE;
  unsigned short* wt_o = wt + (size_t)3 * EE * EE;
  unsigned short* wt_f = wt + (size_t)4 * EE * EE;

  k_detect<<<1, 256, 0, stream>>>((const unsigned char*)ma, flag);
  k_pe<<<(SS * EE + 255) / 256, 256, 0, stream>>>(pe);
  k_trans<<<dim3(EE / 32, EE / 32, 5), dim3(32, 8), 0, stream>>>(qw, kw, vw, ow, fw, wt);
  k_cast<<<(EE * EE / 8 + 255) / 256, 256, 0, stream>>>(kw, kwb);
  k_lastidx<<<(2 * BB + 255) / 256, 256, 0, stream>>>(ma, mb, flag, lastidx);

  for (int br = 0; br < 2; ++br) {
    const float* xin = br ? bv : av;
    const int* li = lastidx + br * BB;
    k_ln<<<MROWS, 256, 0, stream>>>(xin, pe, lng, lnb, li, xln, lastx);
    // Q projection: q = lastx @ Wq + qb   [4096 x 1536]
    k_gemm_g<0><<<dim3(32 * 12, 1), 256, 0, stream>>>(
        lastx, 0, EE, wt_q, 0, EE, qb, 0, qbuf, 0, EE, 32, 12, EE);
    // qk[b,h][e] = sum_d q[b,h,d] * Wk[e, h*128+d]; B[n=e][k=d] = kwb[e][h*128+d]
    // per h: [4096 x 128] @ -> [4096 x 1536] planes of qky
    k_gemm_g<0><<<dim3(32 * 12, HH), 256, 0, stream>>>(
        qbuf, HDIM, EE, kwb, HDIM, EE, nullptr, 0, qky, EE, HH * EE, 32, 12, HDIM);
    // scores + softmax + weighted sum -> y (in place over qky)
    k_attn2<<<BB, 256, 0, stream>>>(xln, qky, li);
    // ctx[b,hblk] = y[b,h] @ Wv[:,hblk] + bv  (per h: [4096x1536]@[1536x128])
    k_gemm_g<0><<<dim3(32 * 1, HH), 256, 0, stream>>>(
        qky, EE, HH * EE, wt_v, HDIM * EE, EE, vbs, HDIM,
        ctx + (size_t)br * BB * EE, HDIM, EE, 32, 1, EE);
  }
  // batched O projection over both branches: [8192 x 1536]
  k_gemm_g<0><<<dim3(64 * 12, 1), 256, 0, stream>>>(
      ctx, 0, EE, wt_o, 0, EE, ob, 0, o1, 0, EE, 64, 12, EE);
  // batched F projection + exact GELU -> f32 output (branch-major)
  k_gemm_g<2><<<dim3(64 * 12, 1), 256, 0, stream>>>(
      o1, 0, EE, wt_f, 0, EE, fbs, 0, d_out, 0, EE, 64, 12, EE);
}

// Round 5
// 1012.293 us; speedup vs baseline: 1.7763x; 1.0028x over previous
//
#include <hip/hip_runtime.h>
#include <math.h>

#define BB 4096
#define SS 10
#define EE 1536
#define HH 12
#define HDIM 128
#define MROWS (BB * SS)   // 40960 rows per branch

typedef short short8 __attribute__((ext_vector_type(8)));
typedef float f32x4 __attribute__((ext_vector_type(4)));
typedef const unsigned char __attribute__((address_space(1))) gu8;
typedef unsigned char __attribute__((address_space(3))) lu8;

__device__ __forceinline__ unsigned short f2bf(float x) {
  unsigned int u = __float_as_uint(x);
  return (unsigned short)((u + 0x7FFFu + ((u >> 16) & 1u)) >> 16);
}
__device__ __forceinline__ float bf2f(unsigned short u) {
  return __uint_as_float(((unsigned int)u) << 16);
}

// ---- mask dtype detection (bool bytes vs int32 vs f32) ---------------------
__global__ void k_detect(const unsigned char* __restrict__ m, int* __restrict__ flag) {
  __shared__ int fb, ff;
  if (threadIdx.x == 0) { fb = 0; ff = 0; }
  __syncthreads();
  int lb = 0, lf = 0;
  for (int j = threadIdx.x; j < BB * SS; j += blockDim.x) {
    unsigned char v = m[j];
    if (v) {
      int r = j & 3;
      if (r == 1) lb = 1;
      else if (r >= 2) lf = 1;
    }
  }
  if (lb) atomicOr(&fb, 1);
  if (lf) atomicOr(&ff, 1);
  __syncthreads();
  if (threadIdx.x == 0) *flag = fb ? 1 : (ff ? 2 : 0);
}

__global__ void k_lastidx(const void* __restrict__ ma, const void* __restrict__ mb,
                          const int* __restrict__ flag, int* __restrict__ lastidx) {
  int idx = blockIdx.x * blockDim.x + threadIdx.x;
  if (idx >= 2 * BB) return;
  const void* m = (idx >= BB) ? mb : ma;
  int b = idx & (BB - 1);
  int f = *flag;
  int len = 0;
  for (int s = 0; s < SS; ++s) {
    int j = b * SS + s;
    int pad;
    if (f == 1)      pad = ((const unsigned char*)m)[j] != 0;
    else if (f == 2) pad = ((const float*)m)[j] != 0.0f;
    else             pad = ((const int*)m)[j] != 0;
    len += (pad == 0);
  }
  lastidx[idx] = len - 1;
}

// ---- positional-encoding table --------------------------------------------
__global__ void k_pe(float* __restrict__ pe) {
  int idx = blockIdx.x * blockDim.x + threadIdx.x;
  if (idx >= SS * EE) return;
  int s = idx / EE, e = idx - (idx / EE) * EE;
  float fe = (float)(e & ~1);
  float freq = expf(fe * (-9.210340371976184f / (float)EE));  // -ln(10000)/E
  float arg = (float)s * freq;
  pe[idx] = (e & 1) ? cosf(arg) : sinf(arg);
}

// ---- weight transpose f32[K][N] -> bf16[N][K] ------------------------------
__global__ void k_trans(const float* __restrict__ w0, const float* __restrict__ w1,
                        const float* __restrict__ w2, const float* __restrict__ w3,
                        const float* __restrict__ w4, unsigned short* __restrict__ wt) {
  __shared__ float tile[32][33];
  int z = blockIdx.z;
  const float* W = z == 0 ? w0 : z == 1 ? w1 : z == 2 ? w2 : z == 3 ? w3 : w4;
  unsigned short* T = wt + (size_t)z * EE * EE;
  int n0 = blockIdx.x * 32, k0 = blockIdx.y * 32;
  int tx = threadIdx.x, ty = threadIdx.y;
#pragma unroll
  for (int i = 0; i < 4; ++i)
    tile[ty + i * 8][tx] = W[(size_t)(k0 + ty + i * 8) * EE + n0 + tx];
  __syncthreads();
#pragma unroll
  for (int i = 0; i < 4; ++i)
    T[(size_t)(n0 + ty + i * 8) * EE + k0 + tx] = f2bf(tile[tx][ty + i * 8]);
}

// ---- straight f32 -> bf16 cast (layout preserved) --------------------------
__global__ void k_cast(const float* __restrict__ in, unsigned short* __restrict__ out) {
  int i = (blockIdx.x * blockDim.x + threadIdx.x) * 8;
  if (i >= EE * EE) return;
  float4 a = *(const float4*)(in + i);
  float4 b = *(const float4*)(in + i + 4);
  short8 v;
  v[0] = (short)f2bf(a.x); v[1] = (short)f2bf(a.y);
  v[2] = (short)f2bf(a.z); v[3] = (short)f2bf(a.w);
  v[4] = (short)f2bf(b.x); v[5] = (short)f2bf(b.y);
  v[6] = (short)f2bf(b.z); v[7] = (short)f2bf(b.w);
  *(short8*)(out + i) = v;
}

// ---- fused add-PE + LayerNorm (two-pass, f32) -> bf16 + last-row gather ----
__global__ __launch_bounds__(256) void k_ln(
    const float* __restrict__ xin, const float* __restrict__ pe,
    const float* __restrict__ g, const float* __restrict__ be,
    const int* __restrict__ lastidx,
    unsigned short* __restrict__ xln, unsigned short* __restrict__ lastx) {
  __shared__ float red[4];
  int row = blockIdx.x;
  int b = row / SS, s = row - b * SS;
  const float2* x2 = (const float2*)(xin + (size_t)row * EE);
  const float2* p2 = (const float2*)(pe + s * EE);
  int t = threadIdx.x;
  float2 v[3];
  float lsum = 0.f;
#pragma unroll
  for (int i = 0; i < 3; ++i) {
    int e2 = t + i * 256;
    float2 a = x2[e2], p = p2[e2];
    a.x += p.x; a.y += p.y;
    v[i] = a;
    lsum += a.x + a.y;
  }
  for (int off = 32; off; off >>= 1) lsum += __shfl_xor(lsum, off, 64);
  if ((t & 63) == 0) red[t >> 6] = lsum;
  __syncthreads();
  float mu = (red[0] + red[1] + red[2] + red[3]) * (1.0f / EE);
  __syncthreads();
  float lss = 0.f;
#pragma unroll
  for (int i = 0; i < 3; ++i) {
    float dx = v[i].x - mu, dy = v[i].y - mu;
    lss += dx * dx + dy * dy;
  }
  for (int off = 32; off; off >>= 1) lss += __shfl_xor(lss, off, 64);
  if ((t & 63) == 0) red[t >> 6] = lss;
  __syncthreads();
  float var = (red[0] + red[1] + red[2] + red[3]) * (1.0f / EE);
  float scl = rsqrtf(var + 1e-5f);
  bool isLast = (s == lastidx[b]);
  unsigned int* orow = (unsigned int*)(xln + (size_t)row * EE);
  unsigned int* lrow = (unsigned int*)(lastx + (size_t)b * EE);
  const float2* g2 = (const float2*)g;
  const float2* b2 = (const float2*)be;
#pragma unroll
  for (int i = 0; i < 3; ++i) {
    int e2 = t + i * 256;
    float2 gg = g2[e2], bb = b2[e2];
    float ox = (v[i].x - mu) * scl * gg.x + bb.x;
    float oy = (v[i].y - mu) * scl * gg.y + bb.y;
    unsigned int pk = (unsigned int)f2bf(ox) | ((unsigned int)f2bf(oy) << 16);
    orow[e2] = pk;
    if (isLast) lrow[e2] = pk;
  }
}

// ---- generalized 128x128 m97-structure bf16 GEMM ---------------------------
// C[h-plane][m][n] = sum_k A[h][m][k] * Bt[h][n][k], per-h element offsets
// aStrH/bStrH/cStrH/biasStrH (blockIdx.y = h). EPI 0: +bias -> bf16.
template<int EPI>
__global__ __launch_bounds__(256) void k_gemm_g(
    const unsigned short* __restrict__ A, int aStrH, int lda,
    const unsigned short* __restrict__ Bt, int bStrH, int ldb,
    const float* __restrict__ bias, int biasStrH,
    void* __restrict__ C, int cStrH, int ldc,
    int MB, int NB, int K) {
  __shared__ __align__(16) unsigned char smA[8192];
  __shared__ __align__(16) unsigned char smB[8192];
  int h = blockIdx.y;
  const unsigned char* Ab = (const unsigned char*)(A + (size_t)h * aStrH);
  const unsigned char* Bb = (const unsigned char*)(Bt + (size_t)h * bStrH);
  const float* bi = bias ? bias + (size_t)h * biasStrH : nullptr;
  int per = MB >> 3;
  int bid = blockIdx.x;
  int xcd = bid & 7, lin = bid >> 3;
  int mt = xcd * per + lin / NB;
  int nt = lin % NB;
  int m0 = mt << 7, n0 = nt << 7;
  int tid = threadIdx.x, wid = tid >> 6, lane = tid & 63;
  int wm = wid >> 1, wn = wid & 1;
  f32x4 acc[4][4] = {};
  const size_t ldaB = (size_t)lda * 2, ldbB = (size_t)ldb * 2;
  int lrow = lane & 15, kgrp = lane >> 4;
  int aoff = (wm * 64 + lrow) * 64 + kgrp * 16;
  int boff = (wn * 64 + lrow) * 64 + kgrp * 16;
  int Lbase = wid * 1024 + lane * 16;
  const int nk = K >> 5;
  for (int kt = 0; kt < nk; ++kt) {
    int k0b = kt << 6;
#pragma unroll
    for (int issue = 0; issue < 2; ++issue) {
      int L = issue * 4096 + Lbase;
      int row = L >> 6, colb = L & 63;
      int Lu = issue * 4096 + wid * 1024;
      __builtin_amdgcn_global_load_lds((gu8*)(Ab + (size_t)(m0 + row) * ldaB + k0b + colb),
                                       (lu8*)(smA + Lu), 16, 0, 0);
      __builtin_amdgcn_global_load_lds((gu8*)(Bb + (size_t)(n0 + row) * ldbB + k0b + colb),
                                       (lu8*)(smB + Lu), 16, 0, 0);
    }
    __syncthreads();
    short8 af[4], bfr[4];
#pragma unroll
    for (int i = 0; i < 4; ++i) {
      af[i]  = *(const short8*)(smA + aoff + i * 1024);
      bfr[i] = *(const short8*)(smB + boff + i * 1024);
    }
#pragma unroll
    for (int mi = 0; mi < 4; ++mi)
#pragma unroll
      for (int ni = 0; ni < 4; ++ni)
        acc[mi][ni] = __builtin_amdgcn_mfma_f32_16x16x32_bf16(af[mi], bfr[ni], acc[mi][ni], 0, 0, 0);
    __syncthreads();
  }
  int rbase = m0 + wm * 64 + (lane >> 4) * 4;
  int cbase = n0 + wn * 64 + (lane & 15);
#pragma unroll
  for (int mi = 0; mi < 4; ++mi) {
#pragma unroll
    for (int ni = 0; ni < 4; ++ni) {
      int c = cbase + ni * 16;
      float bv = bi ? bi[c] : 0.f;
#pragma unroll
      for (int j = 0; j < 4; ++j) {
        int r = rbase + mi * 16 + j;
        float val = acc[mi][ni][j] + bv;
        ((unsigned short*)C)[(size_t)h * cStrH + (size_t)r * ldc + c] = f2bf(val);
      }
    }
  }
}

// ---- 256x256 8-phase bf16 GEMM (T1+T2+T3+T4+T5) ----------------------------
// EPI 0: +bias -> bf16.  EPI 2: +bias, exact GELU -> f32.
// Requires (M/256)%8==0 with (M/256/8) divisible by MTG handling (M=8192 ok),
// N%256==0, K%128==0.
#define MMAQ(AR_, BR_, QM, QN)                                                  \
  do {                                                                          \
    _Pragma("unroll")                                                           \
    for (int mi_ = 0; mi_ < 4; ++mi_) {                                         \
      _Pragma("unroll")                                                         \
      for (int ni_ = 0; ni_ < 2; ++ni_) {                                       \
        acc[(QM)*4 + mi_][(QN)*2 + ni_] = __builtin_amdgcn_mfma_f32_16x16x32_bf16( \
            AR_[mi_][0], BR_[ni_][0], acc[(QM)*4 + mi_][(QN)*2 + ni_], 0, 0, 0);   \
        acc[(QM)*4 + mi_][(QN)*2 + ni_] = __builtin_amdgcn_mfma_f32_16x16x32_bf16( \
            AR_[mi_][1], BR_[ni_][1], acc[(QM)*4 + mi_][(QN)*2 + ni_], 0, 0, 0);   \
      }                                                                         \
    }                                                                           \
  } while (0)

#define PHASE_MID()                                      \
  do {                                                   \
    __builtin_amdgcn_s_barrier();                        \
    asm volatile("s_waitcnt lgkmcnt(0)" ::: "memory");   \
    __builtin_amdgcn_s_setprio(1);                       \
  } while (0)
#define PHASE_END()                                      \
  do {                                                   \
    __builtin_amdgcn_s_setprio(0);                       \
    __builtin_amdgcn_s_barrier();                        \
  } while (0)

template<int EPI>
__global__ __launch_bounds__(512, 2) void k_gemm256(
    const unsigned short* __restrict__ A, const unsigned short* __restrict__ Bt,
    const float* __restrict__ bias,
    void* __restrict__ C, int M, int N, int K) {
  __shared__ __align__(16) unsigned char lds[131072];
  const int NT = K >> 6;
  const int niters = NT >> 1;
  const int Ntiles = N >> 8;
  const int perx = (M >> 8) >> 3;
  const int MTG = 4;
  int bid = blockIdx.x;
  int xcd = bid & 7, lin = bid >> 3;
  int grp = lin / (MTG * Ntiles);
  int rem = lin - grp * (MTG * Ntiles);
  int nt = rem / MTG, mi_ = rem - nt * MTG;
  int mt = xcd * perx + grp * MTG + mi_;
  int m0 = mt << 8, n0 = nt << 8;
  int tid = threadIdx.x;
  int w = tid >> 6, lane = tid & 63;
  int wm = w >> 2, wn = w & 3;
  const size_t lda = (size_t)K * 2;
  const unsigned char* Ag = (const unsigned char*)A;
  const unsigned char* Bg = (const unsigned char*)Bt;

  unsigned char* A0 = lds;
  unsigned char* B0 = lds + 32768;
  unsigned char* A1 = lds + 65536;
  unsigned char* B1 = lds + 98304;

  int lrows = lane >> 3;
  int colswz = (((lane & 7) ^ (lrows & 7)) << 4);
  int rowA = w * 8;
  int rowB = (w >> 2) * 64 + (w & 3) * 8;

  auto stageA = [&](unsigned char* ldsA, int q, int kt) {
    int cb = kt * 128 + colswz;
#pragma unroll
    for (int i = 0; i < 2; ++i) {
      int tr = q * 64 + i * 128 + rowA;
      __builtin_amdgcn_global_load_lds(
          (gu8*)(Ag + (size_t)(m0 + tr + lrows) * lda + cb),
          (lu8*)(ldsA + tr * 128), 16, 0, 0);
    }
  };
  auto stageB = [&](unsigned char* ldsB, int q, int kt) {
    int cb = kt * 128 + colswz;
#pragma unroll
    for (int i = 0; i < 2; ++i) {
      int tr = q * 32 + i * 128 + rowB;
      __builtin_amdgcn_global_load_lds(
          (gu8*)(Bg + (size_t)(n0 + tr + lrows) * lda + cb),
          (lu8*)(ldsB + tr * 128), 16, 0, 0);
    }
  };

  int lrow = lane & 15, kgrp = lane >> 4, r7 = lane & 7;
  int s0 = ((kgrp ^ r7) << 4), s1 = (((kgrp | 4) ^ r7) << 4);
  int abase = (wm * 128 + lrow) * 128;
  int bbase = (wn * 64 + lrow) * 128;

  short8 ar[4][2], br0[2][2], br1[2][2];
  f32x4 acc[8][4];
#pragma unroll
  for (int i = 0; i < 8; ++i)
#pragma unroll
    for (int j = 0; j < 4; ++j) acc[i][j] = (f32x4)0.f;

  auto ldA = [&](unsigned char* ldsA, int qm) {
#pragma unroll
    for (int mi2 = 0; mi2 < 4; ++mi2) {
      ar[mi2][0] = *(const short8*)(ldsA + abase + qm * 8192 + mi2 * 2048 + s0);
      ar[mi2][1] = *(const short8*)(ldsA + abase + qm * 8192 + mi2 * 2048 + s1);
    }
  };
  auto ldB = [&](unsigned char* ldsB, int qn, short8 (&br)[2][2]) {
#pragma unroll
    for (int ni2 = 0; ni2 < 2; ++ni2) {
      br[ni2][0] = *(const short8*)(ldsB + bbase + qn * 4096 + ni2 * 2048 + s0);
      br[ni2][1] = *(const short8*)(ldsB + bbase + qn * 4096 + ni2 * 2048 + s1);
    }
  };

  stageA(A0, 0, 0); stageB(B0, 0, 0); stageA(A0, 1, 0); stageB(B0, 1, 0);
  stageA(A1, 0, 1); stageB(B1, 0, 1);
  asm volatile("s_waitcnt vmcnt(8)" ::: "memory");
  __builtin_amdgcn_s_barrier();

  for (int it = 0; it < niters - 1; ++it) {
    int t1 = 2 * it + 1, t2 = 2 * it + 2, t3 = 2 * it + 3;
    ldA(A0, 0); ldB(B0, 0, br0);
    stageA(A1, 1, t1);
    asm volatile("s_waitcnt vmcnt(6)" ::: "memory");
    PHASE_MID(); MMAQ(ar, br0, 0, 0); PHASE_END();
    ldB(B0, 1, br1);
    stageB(B1, 1, t1);
    PHASE_MID(); MMAQ(ar, br1, 0, 1); PHASE_END();
    ldA(A0, 1);
    stageA(A0, 0, t2);
    PHASE_MID(); MMAQ(ar, br0, 1, 0); PHASE_END();
    stageB(B0, 0, t2);
    asm volatile("s_waitcnt vmcnt(8)" ::: "memory");
    PHASE_MID(); MMAQ(ar, br1, 1, 1); PHASE_END();
    ldA(A1, 0); ldB(B1, 0, br0);
    stageA(A0, 1, t2);
    asm volatile("s_waitcnt vmcnt(6)" ::: "memory");
    PHASE_MID(); MMAQ(ar, br0, 0, 0); PHASE_END();
    ldB(B1, 1, br1);
    stageB(B0, 1, t2);
    PHASE_MID(); MMAQ(ar, br1, 0, 1); PHASE_END();
    ldA(A1, 1);
    if (t3 < NT) stageA(A1, 0, t3);
    PHASE_MID(); MMAQ(ar, br0, 1, 0); PHASE_END();
    if (t3 < NT) stageB(B1, 0, t3);
    asm volatile("s_waitcnt vmcnt(8)" ::: "memory");
    PHASE_MID(); MMAQ(ar, br1, 1, 1); PHASE_END();
  }
  {
    int t1 = NT - 1;
    ldA(A0, 0); ldB(B0, 0, br0);
    stageA(A1, 1, t1);
    asm volatile("s_waitcnt vmcnt(6)" ::: "memory");
    PHASE_MID(); MMAQ(ar, br0, 0, 0); PHASE_END();
    ldB(B0, 1, br1);
    stageB(B1, 1, t1);
    PHASE_MID(); MMAQ(ar, br1, 0, 1); PHASE_END();
    ldA(A0, 1);
    PHASE_MID(); MMAQ(ar, br0, 1, 0); PHASE_END();
    asm volatile("s_waitcnt vmcnt(4)" ::: "memory");
    PHASE_MID(); MMAQ(ar, br1, 1, 1); PHASE_END();
    ldA(A1, 0); ldB(B1, 0, br0);
    asm volatile("s_waitcnt vmcnt(2)" ::: "memory");
    PHASE_MID(); MMAQ(ar, br0, 0, 0); PHASE_END();
    ldB(B1, 1, br1);
    asm volatile("s_waitcnt vmcnt(0)" ::: "memory");
    PHASE_MID(); MMAQ(ar, br1, 0, 1); PHASE_END();
    ldA(A1, 1);
    PHASE_MID(); MMAQ(ar, br0, 1, 0); PHASE_END();
    PHASE_MID(); MMAQ(ar, br1, 1, 1); PHASE_END();
  }

  int rb = m0 + wm * 128 + (lane >> 4) * 4;
  int cb2 = n0 + wn * 64 + (lane & 15);
#pragma unroll
  for (int fm = 0; fm < 8; ++fm)
#pragma unroll
    for (int fn = 0; fn < 4; ++fn) {
      int c = cb2 + fn * 16;
      float bv = bias[c];
#pragma unroll
      for (int j = 0; j < 4; ++j) {
        int r = rb + fm * 16 + j;
        float val = acc[fm][fn][j] + bv;
        if (EPI == 2) {
          val = 0.5f * val * (1.0f + erff(val * 0.7071067811865476f));
          ((float*)C)[(size_t)r * N + c] = val;
        } else {
          ((unsigned short*)C)[(size_t)r * N + c] = f2bf(val);
        }
      }
    }
}

// ---- fused scores + softmax + weighted-sum (low-LDS version) ---------------
// Per block b: S[h,s] = qk[b,h].x_ln[b,s]; MFMA A-operand read directly from
// global qk (block touches only 37 KB, L2-served). LDS: x rows only (~36 KB)
// -> 4 blocks/CU occupancy. y[b,h] = sum_s w[h,s] x[b,s] overwrites qk.
__global__ __launch_bounds__(256) void k_attn2(
    const unsigned short* __restrict__ xln,   // [BB*SS][EE]
    unsigned short* qky,                      // [BB][HH*EE]  in: qk, out: y
    const int* __restrict__ lastidx) {
  __shared__ __align__(16) unsigned short xs[10 * 1544];
  __shared__ float swp[4 * 256];
  __shared__ float scf[120];
  __shared__ float wsm[120];
  int b = blockIdx.x;
  int t = threadIdx.x;
  const unsigned short* xg = xln + (size_t)b * SS * EE;
  unsigned short* qg = qky + (size_t)b * HH * EE;
  // cooperative load x (10x1536) into padded LDS
#pragma unroll
  for (int j = 0; j < 8; ++j) {
    int idx = t + j * 256;
    if (idx < 1920) {
      int row = idx / 192, col = (idx - row * 192) * 8;
      *(short8*)(xs + row * 1544 + col) = *(const short8*)(xg + row * 1536 + col);
    }
  }
  __syncthreads();
  int w = t >> 6, lane = t & 63;
  // scores: one 16x16 tile, K split across 4 waves; A frag from global
  {
    int hr = lane & 15; if (hr > 11) hr = 11;   // A row (head), clamp
    int sr = lane & 15; if (sr > 9) sr = 9;     // B row (seq), clamp
    int kg = lane >> 4;
    f32x4 pacc = (f32x4)0.f;
#pragma unroll
    for (int kt = 0; kt < 12; ++kt) {
      int k0 = w * 384 + kt * 32 + kg * 8;
      short8 a  = *(const short8*)(qg + hr * 1536 + k0);
      short8 bf = *(const short8*)(xs + sr * 1544 + k0);
      pacc = __builtin_amdgcn_mfma_f32_16x16x32_bf16(a, bf, pacc, 0, 0, 0);
    }
    int prow = (lane >> 4) * 4, pcol = lane & 15;
#pragma unroll
    for (int j = 0; j < 4; ++j)
      swp[w * 256 + (prow + j) * 16 + pcol] = pacc[j];
  }
  __syncthreads();
  if (t < 120) {
    int h = t / 10, s = t - (t / 10) * 10;
    float v = swp[h * 16 + s] + swp[256 + h * 16 + s] +
              swp[512 + h * 16 + s] + swp[768 + h * 16 + s];
    scf[t] = v * 0.08838834764831845f;  // HD^-0.5
  }
  __syncthreads();
  int li = lastidx[b];
  if (t < 12) {
    float mx = -1e30f;
    for (int s = 0; s <= li; ++s) mx = fmaxf(mx, scf[t * 10 + s]);
    float sum = 0.f;
    for (int s = 0; s <= li; ++s) {
      float e = expf(scf[t * 10 + s] - mx);
      wsm[t * 10 + s] = e; sum += e;
    }
    float inv = 1.0f / sum;
    for (int s = 0; s <= li; ++s) wsm[t * 10 + s] *= inv;
  }
  __syncthreads();
  // y phase: wave w handles heads 3w..3w+2; lane covers 2 e's per pass
  float wv[3][10];
#pragma unroll
  for (int hl = 0; hl < 3; ++hl)
#pragma unroll
    for (int s = 0; s < 10; ++s)
      wv[hl][s] = (s <= li) ? wsm[(3 * w + hl) * 10 + s] : 0.f;
#pragma unroll
  for (int pass = 0; pass < 12; ++pass) {
    int e0 = pass * 128 + lane * 2;
    float acc[3][2] = {};
    for (int s = 0; s <= li; ++s) {
      unsigned int x2 = *(const unsigned int*)(xs + s * 1544 + e0);
      float xlo = bf2f((unsigned short)(x2 & 0xffff));
      float xhi = bf2f((unsigned short)(x2 >> 16));
#pragma unroll
      for (int hl = 0; hl < 3; ++hl) {
        acc[hl][0] += wv[hl][s] * xlo;
        acc[hl][1] += wv[hl][s] * xhi;
      }
    }
#pragma unroll
    for (int hl = 0; hl < 3; ++hl) {
      unsigned int pk = (unsigned int)f2bf(acc[hl][0]) | ((unsigned int)f2bf(acc[hl][1]) << 16);
      *(unsigned int*)(qg + (3 * w + hl) * 1536 + e0) = pk;
    }
  }
}

extern "C" void kernel_launch(void* const* d_in, const int* in_sizes, int n_in,
                              void* d_out, int out_size, void* d_ws, size_t ws_size,
                              hipStream_t stream) {
  (void)in_sizes; (void)n_in; (void)out_size; (void)ws_size;
  const float* av  = (const float*)d_in[0];
  const float* bv  = (const float*)d_in[1];
  const void*  ma  = d_in[2];
  const void*  mb  = d_in[3];
  const float* qw  = (const float*)d_in[4];
  const float* qb  = (const float*)d_in[5];
  const float* kw  = (const float*)d_in[6];
  const float* kb  = (const float*)d_in[7];  (void)kb;  // softmax-invariant, dropped
  const float* vw  = (const float*)d_in[8];
  const float* vbs = (const float*)d_in[9];
  const float* ow  = (const float*)d_in[10];
  const float* ob  = (const float*)d_in[11];
  const float* fw  = (const float*)d_in[12];
  const float* fbs = (const float*)d_in[13];
  const float* lng = (const float*)d_in[14];
  const float* lnb = (const float*)d_in[15];

  unsigned char* ws = (unsigned char*)d_ws;
  size_t off = 0;
  auto alloc = [&](size_t bytes) {
    size_t r = off; off = (off + bytes + 255) & ~(size_t)255; return (void*)(ws + r);
  };
  int* flag             = (int*)alloc(4);
  float* pe             = (float*)alloc((size_t)SS * EE * 4);
  unsigned short* wt    = (unsigned short*)alloc((size_t)5 * EE * EE * 2);
  unsigned short* kwb   = (unsigned short*)alloc((size_t)EE * EE * 2);  // Wk bf16, [in][out]
  int* lastidx          = (int*)alloc((size_t)2 * BB * 4);
  unsigned short* xln   = (unsigned short*)alloc((size_t)MROWS * EE * 2);       // 126 MB
  unsigned short* lastx = (unsigned short*)alloc((size_t)BB * EE * 2);
  unsigned short* qbuf  = (unsigned short*)alloc((size_t)BB * EE * 2);
  unsigned short* qky   = (unsigned short*)alloc((size_t)BB * HH * EE * 2);     // 151 MB
  unsigned short* ctx   = (unsigned short*)alloc((size_t)2 * BB * EE * 2);
  unsigned short* o1    = (unsigned short*)alloc((size_t)2 * BB * EE * 2);

  unsigned short* wt_q = wt;
  unsigned short* wt_v = wt + (size_t)2 * EE * EE;
  unsigned short* wt_o = wt + (size_t)3 * EE * EE;
  unsigned short* wt_f = wt + (size_t)4 * EE * EE;

  k_detect<<<1, 256, 0, stream>>>((const unsigned char*)ma, flag);
  k_pe<<<(SS * EE + 255) / 256, 256, 0, stream>>>(pe);
  k_trans<<<dim3(EE / 32, EE / 32, 5), dim3(32, 8), 0, stream>>>(qw, kw, vw, ow, fw, wt);
  k_cast<<<(EE * EE / 8 + 255) / 256, 256, 0, stream>>>(kw, kwb);
  k_lastidx<<<(2 * BB + 255) / 256, 256, 0, stream>>>(ma, mb, flag, lastidx);

  for (int br = 0; br < 2; ++br) {
    const float* xin = br ? bv : av;
    const int* li = lastidx + br * BB;
    k_ln<<<MROWS, 256, 0, stream>>>(xin, pe, lng, lnb, li, xln, lastx);
    // Q projection: q = lastx @ Wq + qb   [4096 x 1536]
    k_gemm_g<0><<<dim3(32 * 12, 1), 256, 0, stream>>>(
        lastx, 0, EE, wt_q, 0, EE, qb, 0, qbuf, 0, EE, 32, 12, EE);
    // qk[b,h][e] = sum_d q[b,h,d] * Wk[e, h*128+d]; B[n=e][k=d] = kwb[e][h*128+d]
    k_gemm_g<0><<<dim3(32 * 12, HH), 256, 0, stream>>>(
        qbuf, HDIM, EE, kwb, HDIM, EE, nullptr, 0, qky, EE, HH * EE, 32, 12, HDIM);
    // scores + softmax + weighted sum -> y (in place over qky)
    k_attn2<<<BB, 256, 0, stream>>>(xln, qky, li);
    // ctx[b,hblk] = y[b,h] @ Wv[:,hblk] + bv  (per h: [4096x1536]@[1536x128])
    k_gemm_g<0><<<dim3(32 * 1, HH), 256, 0, stream>>>(
        qky, EE, HH * EE, wt_v, HDIM * EE, EE, vbs, HDIM,
        ctx + (size_t)br * BB * EE, HDIM, EE, 32, 1, EE);
  }
  // batched O projection over both branches: [8192 x 1536], 8-phase 256^2
  k_gemm256<0><<<(2 * BB / 256) * (EE / 256), 512, 0, stream>>>(
      ctx, wt_o, ob, o1, 2 * BB, EE, EE);
  // batched F projection + exact GELU -> f32 output (branch-major)
  k_gemm256<2><<<(2 * BB / 256) * (EE / 256), 512, 0, stream>>>(
      o1, wt_f, fbs, d_out, 2 * BB, EE, EE);
}

// Round 6
// 941.926 us; speedup vs baseline: 1.9090x; 1.0747x over previous
//
#include <hip/hip_runtime.h>
#include <math.h>

#define BB 4096
#define SS 10
#define EE 1536
#define HH 12
#define HDIM 128
#define MROWS (BB * SS)    // 40960 rows per branch
#define BB2 (2 * BB)       // both branches
#define MROWS2 (2 * MROWS)

typedef short short8 __attribute__((ext_vector_type(8)));
typedef float f32x4 __attribute__((ext_vector_type(4)));
typedef const unsigned char __attribute__((address_space(1))) gu8;
typedef unsigned char __attribute__((address_space(3))) lu8;

__device__ __forceinline__ unsigned short f2bf(float x) {
  unsigned int u = __float_as_uint(x);
  return (unsigned short)((u + 0x7FFFu + ((u >> 16) & 1u)) >> 16);
}
__device__ __forceinline__ float bf2f(unsigned short u) {
  return __uint_as_float(((unsigned int)u) << 16);
}

// ---- mask dtype detection (bool bytes vs int32 vs f32) ---------------------
__global__ void k_detect(const unsigned char* __restrict__ m, int* __restrict__ flag) {
  __shared__ int fb, ff;
  if (threadIdx.x == 0) { fb = 0; ff = 0; }
  __syncthreads();
  int lb = 0, lf = 0;
  for (int j = threadIdx.x; j < BB * SS; j += blockDim.x) {
    unsigned char v = m[j];
    if (v) {
      int r = j & 3;
      if (r == 1) lb = 1;
      else if (r >= 2) lf = 1;
    }
  }
  if (lb) atomicOr(&fb, 1);
  if (lf) atomicOr(&ff, 1);
  __syncthreads();
  if (threadIdx.x == 0) *flag = fb ? 1 : (ff ? 2 : 0);
}

__global__ void k_lastidx(const void* __restrict__ ma, const void* __restrict__ mb,
                          const int* __restrict__ flag, int* __restrict__ lastidx) {
  int idx = blockIdx.x * blockDim.x + threadIdx.x;
  if (idx >= BB2) return;
  const void* m = (idx >= BB) ? mb : ma;
  int b = idx & (BB - 1);
  int f = *flag;
  int len = 0;
  for (int s = 0; s < SS; ++s) {
    int j = b * SS + s;
    int pad;
    if (f == 1)      pad = ((const unsigned char*)m)[j] != 0;
    else if (f == 2) pad = ((const float*)m)[j] != 0.0f;
    else             pad = ((const int*)m)[j] != 0;
    len += (pad == 0);
  }
  lastidx[idx] = len - 1;
}

// ---- positional-encoding table --------------------------------------------
__global__ void k_pe(float* __restrict__ pe) {
  int idx = blockIdx.x * blockDim.x + threadIdx.x;
  if (idx >= SS * EE) return;
  int s = idx / EE, e = idx - (idx / EE) * EE;
  float fe = (float)(e & ~1);
  float freq = expf(fe * (-9.210340371976184f / (float)EE));  // -ln(10000)/E
  float arg = (float)s * freq;
  pe[idx] = (e & 1) ? cosf(arg) : sinf(arg);
}

// ---- weight transpose f32[K][N] -> bf16[N][K] ------------------------------
__global__ void k_trans(const float* __restrict__ w0, const float* __restrict__ w1,
                        const float* __restrict__ w2, const float* __restrict__ w3,
                        const float* __restrict__ w4, unsigned short* __restrict__ wt) {
  __shared__ float tile[32][33];
  int z = blockIdx.z;
  const float* W = z == 0 ? w0 : z == 1 ? w1 : z == 2 ? w2 : z == 3 ? w3 : w4;
  unsigned short* T = wt + (size_t)z * EE * EE;
  int n0 = blockIdx.x * 32, k0 = blockIdx.y * 32;
  int tx = threadIdx.x, ty = threadIdx.y;
#pragma unroll
  for (int i = 0; i < 4; ++i)
    tile[ty + i * 8][tx] = W[(size_t)(k0 + ty + i * 8) * EE + n0 + tx];
  __syncthreads();
#pragma unroll
  for (int i = 0; i < 4; ++i)
    T[(size_t)(n0 + ty + i * 8) * EE + k0 + tx] = f2bf(tile[tx][ty + i * 8]);
}

// ---- straight f32 -> bf16 cast (layout preserved) --------------------------
__global__ void k_cast(const float* __restrict__ in, unsigned short* __restrict__ out) {
  int i = (blockIdx.x * blockDim.x + threadIdx.x) * 8;
  if (i >= EE * EE) return;
  float4 a = *(const float4*)(in + i);
  float4 b = *(const float4*)(in + i + 4);
  short8 v;
  v[0] = (short)f2bf(a.x); v[1] = (short)f2bf(a.y);
  v[2] = (short)f2bf(a.z); v[3] = (short)f2bf(a.w);
  v[4] = (short)f2bf(b.x); v[5] = (short)f2bf(b.y);
  v[6] = (short)f2bf(b.z); v[7] = (short)f2bf(b.w);
  *(short8*)(out + i) = v;
}

// ---- fused add-PE + LayerNorm, both branches in one grid -------------------
// row = blockIdx.x in [0, 2*MROWS); branch picked by row (wave-uniform).
__global__ __launch_bounds__(256) void k_ln(
    const float* __restrict__ av, const float* __restrict__ bv,
    const float* __restrict__ pe,
    const float* __restrict__ g, const float* __restrict__ be,
    const int* __restrict__ lastidx,
    unsigned short* __restrict__ xln, unsigned short* __restrict__ lastx) {
  __shared__ float red[4];
  int row = blockIdx.x;                       // global row (both branches)
  const float* xin = (row < MROWS) ? (av + (size_t)row * EE)
                                   : (bv + (size_t)(row - MROWS) * EE);
  int bg = row / SS, s = row - bg * SS;       // bg in [0, 2*BB)
  const float2* x2 = (const float2*)xin;
  const float2* p2 = (const float2*)(pe + s * EE);
  int t = threadIdx.x;
  float2 v[3];
  float lsum = 0.f;
#pragma unroll
  for (int i = 0; i < 3; ++i) {
    int e2 = t + i * 256;
    float2 a = x2[e2], p = p2[e2];
    a.x += p.x; a.y += p.y;
    v[i] = a;
    lsum += a.x + a.y;
  }
  for (int off = 32; off; off >>= 1) lsum += __shfl_xor(lsum, off, 64);
  if ((t & 63) == 0) red[t >> 6] = lsum;
  __syncthreads();
  float mu = (red[0] + red[1] + red[2] + red[3]) * (1.0f / EE);
  __syncthreads();
  float lss = 0.f;
#pragma unroll
  for (int i = 0; i < 3; ++i) {
    float dx = v[i].x - mu, dy = v[i].y - mu;
    lss += dx * dx + dy * dy;
  }
  for (int off = 32; off; off >>= 1) lss += __shfl_xor(lss, off, 64);
  if ((t & 63) == 0) red[t >> 6] = lss;
  __syncthreads();
  float var = (red[0] + red[1] + red[2] + red[3]) * (1.0f / EE);
  float scl = rsqrtf(var + 1e-5f);
  bool isLast = (s == lastidx[bg]);
  unsigned int* orow = (unsigned int*)(xln + (size_t)row * EE);
  unsigned int* lrow = (unsigned int*)(lastx + (size_t)bg * EE);
  const float2* g2 = (const float2*)g;
  const float2* b2 = (const float2*)be;
#pragma unroll
  for (int i = 0; i < 3; ++i) {
    int e2 = t + i * 256;
    float2 gg = g2[e2], bb = b2[e2];
    float ox = (v[i].x - mu) * scl * gg.x + bb.x;
    float oy = (v[i].y - mu) * scl * gg.y + bb.y;
    unsigned int pk = (unsigned int)f2bf(ox) | ((unsigned int)f2bf(oy) << 16);
    orow[e2] = pk;
    if (isLast) lrow[e2] = pk;
  }
}

// ---- generalized 128x128 m97-structure bf16 GEMM ---------------------------
// C[h-plane][m][n] = sum_k A[h][m][k] * Bt[h][n][k], per-h element offsets
// aStrH/bStrH/cStrH/biasStrH (blockIdx.y = h). +bias -> bf16.
__global__ __launch_bounds__(256) void k_gemm_g(
    const unsigned short* __restrict__ A, int aStrH, int lda,
    const unsigned short* __restrict__ Bt, int bStrH, int ldb,
    const float* __restrict__ bias, int biasStrH,
    void* __restrict__ C, int cStrH, int ldc,
    int MB, int NB, int K) {
  __shared__ __align__(16) unsigned char smA[8192];
  __shared__ __align__(16) unsigned char smB[8192];
  int h = blockIdx.y;
  const unsigned char* Ab = (const unsigned char*)(A + (size_t)h * aStrH);
  const unsigned char* Bb = (const unsigned char*)(Bt + (size_t)h * bStrH);
  const float* bi = bias ? bias + (size_t)h * biasStrH : nullptr;
  int per = MB >> 3;
  int bid = blockIdx.x;
  int xcd = bid & 7, lin = bid >> 3;
  int mt = xcd * per + lin / NB;
  int nt = lin % NB;
  int m0 = mt << 7, n0 = nt << 7;
  int tid = threadIdx.x, wid = tid >> 6, lane = tid & 63;
  int wm = wid >> 1, wn = wid & 1;
  f32x4 acc[4][4] = {};
  const size_t ldaB = (size_t)lda * 2, ldbB = (size_t)ldb * 2;
  int lrow = lane & 15, kgrp = lane >> 4;
  int aoff = (wm * 64 + lrow) * 64 + kgrp * 16;
  int boff = (wn * 64 + lrow) * 64 + kgrp * 16;
  int Lbase = wid * 1024 + lane * 16;
  const int nk = K >> 5;
  for (int kt = 0; kt < nk; ++kt) {
    int k0b = kt << 6;
#pragma unroll
    for (int issue = 0; issue < 2; ++issue) {
      int L = issue * 4096 + Lbase;
      int row = L >> 6, colb = L & 63;
      int Lu = issue * 4096 + wid * 1024;
      __builtin_amdgcn_global_load_lds((gu8*)(Ab + (size_t)(m0 + row) * ldaB + k0b + colb),
                                       (lu8*)(smA + Lu), 16, 0, 0);
      __builtin_amdgcn_global_load_lds((gu8*)(Bb + (size_t)(n0 + row) * ldbB + k0b + colb),
                                       (lu8*)(smB + Lu), 16, 0, 0);
    }
    __syncthreads();
    short8 af[4], bfr[4];
#pragma unroll
    for (int i = 0; i < 4; ++i) {
      af[i]  = *(const short8*)(smA + aoff + i * 1024);
      bfr[i] = *(const short8*)(smB + boff + i * 1024);
    }
#pragma unroll
    for (int mi = 0; mi < 4; ++mi)
#pragma unroll
      for (int ni = 0; ni < 4; ++ni)
        acc[mi][ni] = __builtin_amdgcn_mfma_f32_16x16x32_bf16(af[mi], bfr[ni], acc[mi][ni], 0, 0, 0);
    __syncthreads();
  }
  int rbase = m0 + wm * 64 + (lane >> 4) * 4;
  int cbase = n0 + wn * 64 + (lane & 15);
#pragma unroll
  for (int mi = 0; mi < 4; ++mi) {
#pragma unroll
    for (int ni = 0; ni < 4; ++ni) {
      int c = cbase + ni * 16;
      float bv = bi ? bi[c] : 0.f;
#pragma unroll
      for (int j = 0; j < 4; ++j) {
        int r = rbase + mi * 16 + j;
        float val = acc[mi][ni][j] + bv;
        ((unsigned short*)C)[(size_t)h * cStrH + (size_t)r * ldc + c] = f2bf(val);
      }
    }
  }
}

// ---- 256x256 8-phase bf16 GEMM (T1+T2+T3+T4+T5) ----------------------------
#define MMAQ(AR_, BR_, QM, QN)                                                  \
  do {                                                                          \
    _Pragma("unroll")                                                           \
    for (int mi_ = 0; mi_ < 4; ++mi_) {                                         \
      _Pragma("unroll")                                                         \
      for (int ni_ = 0; ni_ < 2; ++ni_) {                                       \
        acc[(QM)*4 + mi_][(QN)*2 + ni_] = __builtin_amdgcn_mfma_f32_16x16x32_bf16( \
            AR_[mi_][0], BR_[ni_][0], acc[(QM)*4 + mi_][(QN)*2 + ni_], 0, 0, 0);   \
        acc[(QM)*4 + mi_][(QN)*2 + ni_] = __builtin_amdgcn_mfma_f32_16x16x32_bf16( \
            AR_[mi_][1], BR_[ni_][1], acc[(QM)*4 + mi_][(QN)*2 + ni_], 0, 0, 0);   \
      }                                                                         \
    }                                                                           \
  } while (0)

#define PHASE_MID()                                      \
  do {                                                   \
    __builtin_amdgcn_s_barrier();                        \
    asm volatile("s_waitcnt lgkmcnt(0)" ::: "memory");   \
    __builtin_amdgcn_s_setprio(1);                       \
  } while (0)
#define PHASE_END()                                      \
  do {                                                   \
    __builtin_amdgcn_s_setprio(0);                       \
    __builtin_amdgcn_s_barrier();                        \
  } while (0)

template<int EPI>
__global__ __launch_bounds__(512, 2) void k_gemm256(
    const unsigned short* __restrict__ A, const unsigned short* __restrict__ Bt,
    const float* __restrict__ bias,
    void* __restrict__ C, int M, int N, int K) {
  __shared__ __align__(16) unsigned char lds[131072];
  const int NT = K >> 6;
  const int niters = NT >> 1;
  const int Ntiles = N >> 8;
  const int perx = (M >> 8) >> 3;
  const int MTG = 4;
  int bid = blockIdx.x;
  int xcd = bid & 7, lin = bid >> 3;
  int grp = lin / (MTG * Ntiles);
  int rem = lin - grp * (MTG * Ntiles);
  int nt = rem / MTG, mi_ = rem - nt * MTG;
  int mt = xcd * perx + grp * MTG + mi_;
  int m0 = mt << 8, n0 = nt << 8;
  int tid = threadIdx.x;
  int w = tid >> 6, lane = tid & 63;
  int wm = w >> 2, wn = w & 3;
  const size_t lda = (size_t)K * 2;
  const unsigned char* Ag = (const unsigned char*)A;
  const unsigned char* Bg = (const unsigned char*)Bt;

  unsigned char* A0 = lds;
  unsigned char* B0 = lds + 32768;
  unsigned char* A1 = lds + 65536;
  unsigned char* B1 = lds + 98304;

  int lrows = lane >> 3;
  int colswz = (((lane & 7) ^ (lrows & 7)) << 4);
  int rowA = w * 8;
  int rowB = (w >> 2) * 64 + (w & 3) * 8;

  auto stageA = [&](unsigned char* ldsA, int q, int kt) {
    int cb = kt * 128 + colswz;
#pragma unroll
    for (int i = 0; i < 2; ++i) {
      int tr = q * 64 + i * 128 + rowA;
      __builtin_amdgcn_global_load_lds(
          (gu8*)(Ag + (size_t)(m0 + tr + lrows) * lda + cb),
          (lu8*)(ldsA + tr * 128), 16, 0, 0);
    }
  };
  auto stageB = [&](unsigned char* ldsB, int q, int kt) {
    int cb = kt * 128 + colswz;
#pragma unroll
    for (int i = 0; i < 2; ++i) {
      int tr = q * 32 + i * 128 + rowB;
      __builtin_amdgcn_global_load_lds(
          (gu8*)(Bg + (size_t)(n0 + tr + lrows) * lda + cb),
          (lu8*)(ldsB + tr * 128), 16, 0, 0);
    }
  };

  int lrow = lane & 15, kgrp = lane >> 4, r7 = lane & 7;
  int s0 = ((kgrp ^ r7) << 4), s1 = (((kgrp | 4) ^ r7) << 4);
  int abase = (wm * 128 + lrow) * 128;
  int bbase = (wn * 64 + lrow) * 128;

  short8 ar[4][2], br0[2][2], br1[2][2];
  f32x4 acc[8][4];
#pragma unroll
  for (int i = 0; i < 8; ++i)
#pragma unroll
    for (int j = 0; j < 4; ++j) acc[i][j] = (f32x4)0.f;

  auto ldA = [&](unsigned char* ldsA, int qm) {
#pragma unroll
    for (int mi2 = 0; mi2 < 4; ++mi2) {
      ar[mi2][0] = *(const short8*)(ldsA + abase + qm * 8192 + mi2 * 2048 + s0);
      ar[mi2][1] = *(const short8*)(ldsA + abase + qm * 8192 + mi2 * 2048 + s1);
    }
  };
  auto ldB = [&](unsigned char* ldsB, int qn, short8 (&br)[2][2]) {
#pragma unroll
    for (int ni2 = 0; ni2 < 2; ++ni2) {
      br[ni2][0] = *(const short8*)(ldsB + bbase + qn * 4096 + ni2 * 2048 + s0);
      br[ni2][1] = *(const short8*)(ldsB + bbase + qn * 4096 + ni2 * 2048 + s1);
    }
  };

  stageA(A0, 0, 0); stageB(B0, 0, 0); stageA(A0, 1, 0); stageB(B0, 1, 0);
  stageA(A1, 0, 1); stageB(B1, 0, 1);
  asm volatile("s_waitcnt vmcnt(8)" ::: "memory");
  __builtin_amdgcn_s_barrier();

  for (int it = 0; it < niters - 1; ++it) {
    int t1 = 2 * it + 1, t2 = 2 * it + 2, t3 = 2 * it + 3;
    ldA(A0, 0); ldB(B0, 0, br0);
    stageA(A1, 1, t1);
    asm volatile("s_waitcnt vmcnt(6)" ::: "memory");
    PHASE_MID(); MMAQ(ar, br0, 0, 0); PHASE_END();
    ldB(B0, 1, br1);
    stageB(B1, 1, t1);
    PHASE_MID(); MMAQ(ar, br1, 0, 1); PHASE_END();
    ldA(A0, 1);
    stageA(A0, 0, t2);
    PHASE_MID(); MMAQ(ar, br0, 1, 0); PHASE_END();
    stageB(B0, 0, t2);
    asm volatile("s_waitcnt vmcnt(8)" ::: "memory");
    PHASE_MID(); MMAQ(ar, br1, 1, 1); PHASE_END();
    ldA(A1, 0); ldB(B1, 0, br0);
    stageA(A0, 1, t2);
    asm volatile("s_waitcnt vmcnt(6)" ::: "memory");
    PHASE_MID(); MMAQ(ar, br0, 0, 0); PHASE_END();
    ldB(B1, 1, br1);
    stageB(B0, 1, t2);
    PHASE_MID(); MMAQ(ar, br1, 0, 1); PHASE_END();
    ldA(A1, 1);
    if (t3 < NT) stageA(A1, 0, t3);
    PHASE_MID(); MMAQ(ar, br0, 1, 0); PHASE_END();
    if (t3 < NT) stageB(B1, 0, t3);
    asm volatile("s_waitcnt vmcnt(8)" ::: "memory");
    PHASE_MID(); MMAQ(ar, br1, 1, 1); PHASE_END();
  }
  {
    int t1 = NT - 1;
    ldA(A0, 0); ldB(B0, 0, br0);
    stageA(A1, 1, t1);
    asm volatile("s_waitcnt vmcnt(6)" ::: "memory");
    PHASE_MID(); MMAQ(ar, br0, 0, 0); PHASE_END();
    ldB(B0, 1, br1);
    stageB(B1, 1, t1);
    PHASE_MID(); MMAQ(ar, br1, 0, 1); PHASE_END();
    ldA(A0, 1);
    PHASE_MID(); MMAQ(ar, br0, 1, 0); PHASE_END();
    asm volatile("s_waitcnt vmcnt(4)" ::: "memory");
    PHASE_MID(); MMAQ(ar, br1, 1, 1); PHASE_END();
    ldA(A1, 0); ldB(B1, 0, br0);
    asm volatile("s_waitcnt vmcnt(2)" ::: "memory");
    PHASE_MID(); MMAQ(ar, br0, 0, 0); PHASE_END();
    ldB(B1, 1, br1);
    asm volatile("s_waitcnt vmcnt(0)" ::: "memory");
    PHASE_MID(); MMAQ(ar, br1, 0, 1); PHASE_END();
    ldA(A1, 1);
    PHASE_MID(); MMAQ(ar, br0, 1, 0); PHASE_END();
    PHASE_MID(); MMAQ(ar, br1, 1, 1); PHASE_END();
  }

  int rb = m0 + wm * 128 + (lane >> 4) * 4;
  int cb2 = n0 + wn * 64 + (lane & 15);
#pragma unroll
  for (int fm = 0; fm < 8; ++fm)
#pragma unroll
    for (int fn = 0; fn < 4; ++fn) {
      int c = cb2 + fn * 16;
      float bv = bias[c];
#pragma unroll
      for (int j = 0; j < 4; ++j) {
        int r = rb + fm * 16 + j;
        float val = acc[fm][fn][j] + bv;
        if (EPI == 2) {
          val = 0.5f * val * (1.0f + erff(val * 0.7071067811865476f));
          ((float*)C)[(size_t)r * N + c] = val;
        } else {
          ((unsigned short*)C)[(size_t)r * N + c] = f2bf(val);
        }
      }
    }
}

// ---- fused scores + softmax + weighted-sum (low-LDS, both branches) --------
__global__ __launch_bounds__(256) void k_attn2(
    const unsigned short* __restrict__ xln,   // [2*MROWS][EE]
    unsigned short* qky,                      // [2*BB][HH*EE]  in: qk, out: y
    const int* __restrict__ lastidx) {        // [2*BB]
  __shared__ __align__(16) unsigned short xs[10 * 1544];
  __shared__ float swp[4 * 256];
  __shared__ float scf[120];
  __shared__ float wsm[120];
  int b = blockIdx.x;                         // global batch (both branches)
  int t = threadIdx.x;
  const unsigned short* xg = xln + (size_t)b * SS * EE;
  unsigned short* qg = qky + (size_t)b * HH * EE;
#pragma unroll
  for (int j = 0; j < 8; ++j) {
    int idx = t + j * 256;
    if (idx < 1920) {
      int row = idx / 192, col = (idx - row * 192) * 8;
      *(short8*)(xs + row * 1544 + col) = *(const short8*)(xg + row * 1536 + col);
    }
  }
  __syncthreads();
  int w = t >> 6, lane = t & 63;
  {
    int hr = lane & 15; if (hr > 11) hr = 11;
    int sr = lane & 15; if (sr > 9) sr = 9;
    int kg = lane >> 4;
    f32x4 pacc = (f32x4)0.f;
#pragma unroll
    for (int kt = 0; kt < 12; ++kt) {
      int k0 = w * 384 + kt * 32 + kg * 8;
      short8 a  = *(const short8*)(qg + hr * 1536 + k0);
      short8 bf = *(const short8*)(xs + sr * 1544 + k0);
      pacc = __builtin_amdgcn_mfma_f32_16x16x32_bf16(a, bf, pacc, 0, 0, 0);
    }
    int prow = (lane >> 4) * 4, pcol = lane & 15;
#pragma unroll
    for (int j = 0; j < 4; ++j)
      swp[w * 256 + (prow + j) * 16 + pcol] = pacc[j];
  }
  __syncthreads();
  if (t < 120) {
    int h = t / 10, s = t - (t / 10) * 10;
    float v = swp[h * 16 + s] + swp[256 + h * 16 + s] +
              swp[512 + h * 16 + s] + swp[768 + h * 16 + s];
    scf[t] = v * 0.08838834764831845f;  // HD^-0.5
  }
  __syncthreads();
  int li = lastidx[b];
  if (t < 12) {
    float mx = -1e30f;
    for (int s = 0; s <= li; ++s) mx = fmaxf(mx, scf[t * 10 + s]);
    float sum = 0.f;
    for (int s = 0; s <= li; ++s) {
      float e = expf(scf[t * 10 + s] - mx);
      wsm[t * 10 + s] = e; sum += e;
    }
    float inv = 1.0f / sum;
    for (int s = 0; s <= li; ++s) wsm[t * 10 + s] *= inv;
  }
  __syncthreads();
  float wv[3][10];
#pragma unroll
  for (int hl = 0; hl < 3; ++hl)
#pragma unroll
    for (int s = 0; s < 10; ++s)
      wv[hl][s] = (s <= li) ? wsm[(3 * w + hl) * 10 + s] : 0.f;
#pragma unroll
  for (int pass = 0; pass < 12; ++pass) {
    int e0 = pass * 128 + lane * 2;
    float acc[3][2] = {};
    for (int s = 0; s <= li; ++s) {
      unsigned int x2 = *(const unsigned int*)(xs + s * 1544 + e0);
      float xlo = bf2f((unsigned short)(x2 & 0xffff));
      float xhi = bf2f((unsigned short)(x2 >> 16));
#pragma unroll
      for (int hl = 0; hl < 3; ++hl) {
        acc[hl][0] += wv[hl][s] * xlo;
        acc[hl][1] += wv[hl][s] * xhi;
      }
    }
#pragma unroll
    for (int hl = 0; hl < 3; ++hl) {
      unsigned int pk = (unsigned int)f2bf(acc[hl][0]) | ((unsigned int)f2bf(acc[hl][1]) << 16);
      *(unsigned int*)(qg + (3 * w + hl) * 1536 + e0) = pk;
    }
  }
}

extern "C" void kernel_launch(void* const* d_in, const int* in_sizes, int n_in,
                              void* d_out, int out_size, void* d_ws, size_t ws_size,
                              hipStream_t stream) {
  (void)in_sizes; (void)n_in; (void)out_size; (void)ws_size;
  const float* av  = (const float*)d_in[0];
  const float* bv  = (const float*)d_in[1];
  const void*  ma  = d_in[2];
  const void*  mb  = d_in[3];
  const float* qw  = (const float*)d_in[4];
  const float* qb  = (const float*)d_in[5];
  const float* kw  = (const float*)d_in[6];
  const float* kb  = (const float*)d_in[7];  (void)kb;  // softmax-invariant, dropped
  const float* vw  = (const float*)d_in[8];
  const float* vbs = (const float*)d_in[9];
  const float* ow  = (const float*)d_in[10];
  const float* ob  = (const float*)d_in[11];
  const float* fw  = (const float*)d_in[12];
  const float* fbs = (const float*)d_in[13];
  const float* lng = (const float*)d_in[14];
  const float* lnb = (const float*)d_in[15];

  unsigned char* ws = (unsigned char*)d_ws;
  size_t off = 0;
  auto alloc = [&](size_t bytes) {
    size_t r = off; off = (off + bytes + 255) & ~(size_t)255; return (void*)(ws + r);
  };
  int* flag             = (int*)alloc(4);
  float* pe             = (float*)alloc((size_t)SS * EE * 4);
  unsigned short* wt    = (unsigned short*)alloc((size_t)5 * EE * EE * 2);
  unsigned short* kwb   = (unsigned short*)alloc((size_t)EE * EE * 2);   // Wk bf16, [in][out]
  int* lastidx          = (int*)alloc((size_t)BB2 * 4);
  unsigned short* xln   = (unsigned short*)alloc((size_t)MROWS2 * EE * 2);     // 252 MB
  unsigned short* lastx = (unsigned short*)alloc((size_t)BB2 * EE * 2);        // 25 MB
  unsigned short* qbuf  = (unsigned short*)alloc((size_t)BB2 * EE * 2);        // 25 MB
  unsigned short* qky   = (unsigned short*)alloc((size_t)BB2 * HH * EE * 2);   // 302 MB
  unsigned short* ctx   = (unsigned short*)alloc((size_t)BB2 * EE * 2);        // 25 MB
  unsigned short* o1    = (unsigned short*)alloc((size_t)BB2 * EE * 2);        // 25 MB

  unsigned short* wt_q = wt;
  unsigned short* wt_v = wt + (size_t)2 * EE * EE;
  unsigned short* wt_o = wt + (size_t)3 * EE * EE;
  unsigned short* wt_f = wt + (size_t)4 * EE * EE;

  k_detect<<<1, 256, 0, stream>>>((const unsigned char*)ma, flag);
  k_pe<<<(SS * EE + 255) / 256, 256, 0, stream>>>(pe);
  k_trans<<<dim3(EE / 32, EE / 32, 5), dim3(32, 8), 0, stream>>>(qw, kw, vw, ow, fw, wt);
  k_cast<<<(EE * EE / 8 + 255) / 256, 256, 0, stream>>>(kw, kwb);
  k_lastidx<<<(BB2 + 255) / 256, 256, 0, stream>>>(ma, mb, flag, lastidx);

  // fused add-PE + LN, both branches: 81920 rows
  k_ln<<<MROWS2, 256, 0, stream>>>(av, bv, pe, lng, lnb, lastidx, xln, lastx);
  // Q projection: q = lastx @ Wq + qb   [8192 x 1536]
  k_gemm_g<<<dim3(64 * 12, 1), 256, 0, stream>>>(
      lastx, 0, EE, wt_q, 0, EE, qb, 0, qbuf, 0, EE, 64, 12, EE);
  // qk[b,h][e] = sum_d q[b,h,d] * Wk[e, h*128+d]; B[n=e][k=d] = kwb[e*EE + h*128+d]
  k_gemm_g<<<dim3(64 * 12, HH), 256, 0, stream>>>(
      qbuf, HDIM, EE, kwb, HDIM, EE, nullptr, 0, qky, EE, HH * EE, 64, 12, HDIM);
  // scores + softmax + weighted sum -> y (in place over qky), both branches
  k_attn2<<<BB2, 256, 0, stream>>>(xln, qky, lastidx);
  // ctx[b,hblk] = y[b,h] @ Wv[:,hblk] + bv  (per h: [8192x1536]@[1536x128])
  k_gemm_g<<<dim3(64 * 1, HH), 256, 0, stream>>>(
      qky, EE, HH * EE, wt_v, (size_t)0 + HDIM * EE, EE, vbs, HDIM,
      ctx, HDIM, EE, 64, 1, EE);
  // O projection: [8192 x 1536], 8-phase 256^2
  k_gemm256<0><<<(BB2 / 256) * (EE / 256), 512, 0, stream>>>(
      ctx, wt_o, ob, o1, BB2, EE, EE);
  // F projection + exact GELU -> f32 output (branch-major)
  k_gemm256<2><<<(BB2 / 256) * (EE / 256), 512, 0, stream>>>(
      o1, wt_f, fbs, d_out, BB2, EE, EE);
}

// Round 7
// 906.050 us; speedup vs baseline: 1.9846x; 1.0396x over previous
//
#include <hip/hip_runtime.h>
#include <math.h>

#define BB 4096
#define SS 10
#define EE 1536
#define HH 12
#define HDIM 128
#define MROWS (BB * SS)    // 40960 rows per branch
#define BB2 (2 * BB)       // both branches
#define MROWS2 (2 * MROWS)

typedef short short8 __attribute__((ext_vector_type(8)));
typedef float f32x4 __attribute__((ext_vector_type(4)));
typedef const unsigned char __attribute__((address_space(1))) gu8;
typedef unsigned char __attribute__((address_space(3))) lu8;

__device__ __forceinline__ unsigned short f2bf(float x) {
  unsigned int u = __float_as_uint(x);
  return (unsigned short)((u + 0x7FFFu + ((u >> 16) & 1u)) >> 16);
}
__device__ __forceinline__ float bf2f(unsigned short u) {
  return __uint_as_float(((unsigned int)u) << 16);
}

// ---- mask dtype detection (bool bytes vs int32 vs f32) ---------------------
__global__ void k_detect(const unsigned char* __restrict__ m, int* __restrict__ flag) {
  __shared__ int fb, ff;
  if (threadIdx.x == 0) { fb = 0; ff = 0; }
  __syncthreads();
  int lb = 0, lf = 0;
  for (int j = threadIdx.x; j < BB * SS; j += blockDim.x) {
    unsigned char v = m[j];
    if (v) {
      int r = j & 3;
      if (r == 1) lb = 1;
      else if (r >= 2) lf = 1;
    }
  }
  if (lb) atomicOr(&fb, 1);
  if (lf) atomicOr(&ff, 1);
  __syncthreads();
  if (threadIdx.x == 0) *flag = fb ? 1 : (ff ? 2 : 0);
}

__global__ void k_lastidx(const void* __restrict__ ma, const void* __restrict__ mb,
                          const int* __restrict__ flag, int* __restrict__ lastidx) {
  int idx = blockIdx.x * blockDim.x + threadIdx.x;
  if (idx >= BB2) return;
  const void* m = (idx >= BB) ? mb : ma;
  int b = idx & (BB - 1);
  int f = *flag;
  int len = 0;
  for (int s = 0; s < SS; ++s) {
    int j = b * SS + s;
    int pad;
    if (f == 1)      pad = ((const unsigned char*)m)[j] != 0;
    else if (f == 2) pad = ((const float*)m)[j] != 0.0f;
    else             pad = ((const int*)m)[j] != 0;
    len += (pad == 0);
  }
  lastidx[idx] = len - 1;
}

// ---- positional-encoding table --------------------------------------------
__global__ void k_pe(float* __restrict__ pe) {
  int idx = blockIdx.x * blockDim.x + threadIdx.x;
  if (idx >= SS * EE) return;
  int s = idx / EE, e = idx - (idx / EE) * EE;
  float fe = (float)(e & ~1);
  float freq = expf(fe * (-9.210340371976184f / (float)EE));  // -ln(10000)/E
  float arg = (float)s * freq;
  pe[idx] = (e & 1) ? cosf(arg) : sinf(arg);
}

// ---- weight transpose f32[K][N] -> bf16[N][K] ------------------------------
__global__ void k_trans(const float* __restrict__ w0, const float* __restrict__ w1,
                        const float* __restrict__ w2, const float* __restrict__ w3,
                        const float* __restrict__ w4, unsigned short* __restrict__ wt) {
  __shared__ float tile[32][33];
  int z = blockIdx.z;
  const float* W = z == 0 ? w0 : z == 1 ? w1 : z == 2 ? w2 : z == 3 ? w3 : w4;
  unsigned short* T = wt + (size_t)z * EE * EE;
  int n0 = blockIdx.x * 32, k0 = blockIdx.y * 32;
  int tx = threadIdx.x, ty = threadIdx.y;
#pragma unroll
  for (int i = 0; i < 4; ++i)
    tile[ty + i * 8][tx] = W[(size_t)(k0 + ty + i * 8) * EE + n0 + tx];
  __syncthreads();
#pragma unroll
  for (int i = 0; i < 4; ++i)
    T[(size_t)(n0 + ty + i * 8) * EE + k0 + tx] = f2bf(tile[tx][ty + i * 8]);
}

// ---- straight f32 -> bf16 cast (layout preserved) --------------------------
__global__ void k_cast(const float* __restrict__ in, unsigned short* __restrict__ out) {
  int i = (blockIdx.x * blockDim.x + threadIdx.x) * 8;
  if (i >= EE * EE) return;
  float4 a = *(const float4*)(in + i);
  float4 b = *(const float4*)(in + i + 4);
  short8 v;
  v[0] = (short)f2bf(a.x); v[1] = (short)f2bf(a.y);
  v[2] = (short)f2bf(a.z); v[3] = (short)f2bf(a.w);
  v[4] = (short)f2bf(b.x); v[5] = (short)f2bf(b.y);
  v[6] = (short)f2bf(b.z); v[7] = (short)f2bf(b.w);
  *(short8*)(out + i) = v;
}

// ---- fused add-PE + LayerNorm: wave-per-row, single-pass, no LDS -----------
// 4 waves per block = 4 rows; lane covers 24 elems (6 x float4).
// var = E[x^2] - mu^2 (single pass; x ~ O(1) so cancellation is benign).
__global__ __launch_bounds__(256) void k_ln(
    const float* __restrict__ av, const float* __restrict__ bv,
    const float* __restrict__ pe,
    const float* __restrict__ g, const float* __restrict__ be,
    const int* __restrict__ lastidx,
    unsigned short* __restrict__ xln, unsigned short* __restrict__ lastx) {
  int w = threadIdx.x >> 6, lane = threadIdx.x & 63;
  int row = blockIdx.x * 4 + w;               // global row (both branches)
  const float* xin = (row < MROWS) ? (av + (size_t)row * EE)
                                   : (bv + (size_t)(row - MROWS) * EE);
  int bg = row / SS, s = row - bg * SS;       // bg in [0, 2*BB)
  const float4* x4 = (const float4*)xin;
  const float4* p4 = (const float4*)(pe + s * EE);
  float4 v[6];
  float s1 = 0.f, s2 = 0.f;
#pragma unroll
  for (int j = 0; j < 6; ++j) {
    float4 a = x4[j * 64 + lane], p = p4[j * 64 + lane];
    a.x += p.x; a.y += p.y; a.z += p.z; a.w += p.w;
    v[j] = a;
    s1 += a.x + a.y + a.z + a.w;
    s2 += a.x * a.x + a.y * a.y + a.z * a.z + a.w * a.w;
  }
#pragma unroll
  for (int off = 32; off; off >>= 1) {
    s1 += __shfl_xor(s1, off, 64);
    s2 += __shfl_xor(s2, off, 64);
  }
  float mu = s1 * (1.0f / EE);
  float var = s2 * (1.0f / EE) - mu * mu;
  float scl = rsqrtf(var + 1e-5f);
  bool isLast = (s == lastidx[bg]);
  uint2* orow = (uint2*)(xln + (size_t)row * EE);
  uint2* lrow = (uint2*)(lastx + (size_t)bg * EE);
  const float4* g4 = (const float4*)g;
  const float4* b4 = (const float4*)be;
#pragma unroll
  for (int j = 0; j < 6; ++j) {
    int idx = j * 64 + lane;
    float4 gg = g4[idx], bb = b4[idx];
    float o0 = (v[j].x - mu) * scl * gg.x + bb.x;
    float o1 = (v[j].y - mu) * scl * gg.y + bb.y;
    float o2 = (v[j].z - mu) * scl * gg.z + bb.z;
    float o3 = (v[j].w - mu) * scl * gg.w + bb.w;
    uint2 pk;
    pk.x = (unsigned int)f2bf(o0) | ((unsigned int)f2bf(o1) << 16);
    pk.y = (unsigned int)f2bf(o2) | ((unsigned int)f2bf(o3) << 16);
    orow[idx] = pk;
    if (isLast) lrow[idx] = pk;
  }
}

// ---- generalized 128x128 m97-structure bf16 GEMM ---------------------------
// C[h-plane][m][n] = sum_k A[h][m][k] * Bt[h][n][k], per-h element offsets
// aStrH/bStrH/cStrH/biasStrH (blockIdx.y = h). +bias -> bf16.
__global__ __launch_bounds__(256) void k_gemm_g(
    const unsigned short* __restrict__ A, int aStrH, int lda,
    const unsigned short* __restrict__ Bt, int bStrH, int ldb,
    const float* __restrict__ bias, int biasStrH,
    void* __restrict__ C, int cStrH, int ldc,
    int MB, int NB, int K) {
  __shared__ __align__(16) unsigned char smA[8192];
  __shared__ __align__(16) unsigned char smB[8192];
  int h = blockIdx.y;
  const unsigned char* Ab = (const unsigned char*)(A + (size_t)h * aStrH);
  const unsigned char* Bb = (const unsigned char*)(Bt + (size_t)h * bStrH);
  const float* bi = bias ? bias + (size_t)h * biasStrH : nullptr;
  int per = MB >> 3;
  int bid = blockIdx.x;
  int xcd = bid & 7, lin = bid >> 3;
  int mt = xcd * per + lin / NB;
  int nt = lin % NB;
  int m0 = mt << 7, n0 = nt << 7;
  int tid = threadIdx.x, wid = tid >> 6, lane = tid & 63;
  int wm = wid >> 1, wn = wid & 1;
  f32x4 acc[4][4] = {};
  const size_t ldaB = (size_t)lda * 2, ldbB = (size_t)ldb * 2;
  int lrow = lane & 15, kgrp = lane >> 4;
  int aoff = (wm * 64 + lrow) * 64 + kgrp * 16;
  int boff = (wn * 64 + lrow) * 64 + kgrp * 16;
  int Lbase = wid * 1024 + lane * 16;
  const int nk = K >> 5;
  for (int kt = 0; kt < nk; ++kt) {
    int k0b = kt << 6;
#pragma unroll
    for (int issue = 0; issue < 2; ++issue) {
      int L = issue * 4096 + Lbase;
      int row = L >> 6, colb = L & 63;
      int Lu = issue * 4096 + wid * 1024;
      __builtin_amdgcn_global_load_lds((gu8*)(Ab + (size_t)(m0 + row) * ldaB + k0b + colb),
                                       (lu8*)(smA + Lu), 16, 0, 0);
      __builtin_amdgcn_global_load_lds((gu8*)(Bb + (size_t)(n0 + row) * ldbB + k0b + colb),
                                       (lu8*)(smB + Lu), 16, 0, 0);
    }
    __syncthreads();
    short8 af[4], bfr[4];
#pragma unroll
    for (int i = 0; i < 4; ++i) {
      af[i]  = *(const short8*)(smA + aoff + i * 1024);
      bfr[i] = *(const short8*)(smB + boff + i * 1024);
    }
#pragma unroll
    for (int mi = 0; mi < 4; ++mi)
#pragma unroll
      for (int ni = 0; ni < 4; ++ni)
        acc[mi][ni] = __builtin_amdgcn_mfma_f32_16x16x32_bf16(af[mi], bfr[ni], acc[mi][ni], 0, 0, 0);
    __syncthreads();
  }
  int rbase = m0 + wm * 64 + (lane >> 4) * 4;
  int cbase = n0 + wn * 64 + (lane & 15);
#pragma unroll
  for (int mi = 0; mi < 4; ++mi) {
#pragma unroll
    for (int ni = 0; ni < 4; ++ni) {
      int c = cbase + ni * 16;
      float bv = bi ? bi[c] : 0.f;
#pragma unroll
      for (int j = 0; j < 4; ++j) {
        int r = rbase + mi * 16 + j;
        float val = acc[mi][ni][j] + bv;
        ((unsigned short*)C)[(size_t)h * cStrH + (size_t)r * ldc + c] = f2bf(val);
      }
    }
  }
}

// ---- 256x256 8-phase bf16 GEMM (T1+T2+T3+T4+T5) ----------------------------
#define MMAQ(AR_, BR_, QM, QN)                                                  \
  do {                                                                          \
    _Pragma("unroll")                                                           \
    for (int mi_ = 0; mi_ < 4; ++mi_) {                                         \
      _Pragma("unroll")                                                         \
      for (int ni_ = 0; ni_ < 2; ++ni_) {                                       \
        acc[(QM)*4 + mi_][(QN)*2 + ni_] = __builtin_amdgcn_mfma_f32_16x16x32_bf16( \
            AR_[mi_][0], BR_[ni_][0], acc[(QM)*4 + mi_][(QN)*2 + ni_], 0, 0, 0);   \
        acc[(QM)*4 + mi_][(QN)*2 + ni_] = __builtin_amdgcn_mfma_f32_16x16x32_bf16( \
            AR_[mi_][1], BR_[ni_][1], acc[(QM)*4 + mi_][(QN)*2 + ni_], 0, 0, 0);   \
      }                                                                         \
    }                                                                           \
  } while (0)

#define PHASE_MID()                                      \
  do {                                                   \
    __builtin_amdgcn_s_barrier();                        \
    asm volatile("s_waitcnt lgkmcnt(0)" ::: "memory");   \
    __builtin_amdgcn_s_setprio(1);                       \
  } while (0)
#define PHASE_END()                                      \
  do {                                                   \
    __builtin_amdgcn_s_setprio(0);                       \
    __builtin_amdgcn_s_barrier();                        \
  } while (0)

template<int EPI>
__global__ __launch_bounds__(512, 2) void k_gemm256(
    const unsigned short* __restrict__ A, const unsigned short* __restrict__ Bt,
    const float* __restrict__ bias,
    void* __restrict__ C, int M, int N, int K) {
  __shared__ __align__(16) unsigned char lds[131072];
  const int NT = K >> 6;
  const int niters = NT >> 1;
  const int Ntiles = N >> 8;
  const int perx = (M >> 8) >> 3;
  const int MTG = 4;
  int bid = blockIdx.x;
  int xcd = bid & 7, lin = bid >> 3;
  int grp = lin / (MTG * Ntiles);
  int rem = lin - grp * (MTG * Ntiles);
  int nt = rem / MTG, mi_ = rem - nt * MTG;
  int mt = xcd * perx + grp * MTG + mi_;
  int m0 = mt << 8, n0 = nt << 8;
  int tid = threadIdx.x;
  int w = tid >> 6, lane = tid & 63;
  int wm = w >> 2, wn = w & 3;
  const size_t lda = (size_t)K * 2;
  const unsigned char* Ag = (const unsigned char*)A;
  const unsigned char* Bg = (const unsigned char*)Bt;

  unsigned char* A0 = lds;
  unsigned char* B0 = lds + 32768;
  unsigned char* A1 = lds + 65536;
  unsigned char* B1 = lds + 98304;

  int lrows = lane >> 3;
  int colswz = (((lane & 7) ^ (lrows & 7)) << 4);
  int rowA = w * 8;
  int rowB = (w >> 2) * 64 + (w & 3) * 8;

  auto stageA = [&](unsigned char* ldsA, int q, int kt) {
    int cb = kt * 128 + colswz;
#pragma unroll
    for (int i = 0; i < 2; ++i) {
      int tr = q * 64 + i * 128 + rowA;
      __builtin_amdgcn_global_load_lds(
          (gu8*)(Ag + (size_t)(m0 + tr + lrows) * lda + cb),
          (lu8*)(ldsA + tr * 128), 16, 0, 0);
    }
  };
  auto stageB = [&](unsigned char* ldsB, int q, int kt) {
    int cb = kt * 128 + colswz;
#pragma unroll
    for (int i = 0; i < 2; ++i) {
      int tr = q * 32 + i * 128 + rowB;
      __builtin_amdgcn_global_load_lds(
          (gu8*)(Bg + (size_t)(n0 + tr + lrows) * lda + cb),
          (lu8*)(ldsB + tr * 128), 16, 0, 0);
    }
  };

  int lrow = lane & 15, kgrp = lane >> 4, r7 = lane & 7;
  int s0 = ((kgrp ^ r7) << 4), s1 = (((kgrp | 4) ^ r7) << 4);
  int abase = (wm * 128 + lrow) * 128;
  int bbase = (wn * 64 + lrow) * 128;

  short8 ar[4][2], br0[2][2], br1[2][2];
  f32x4 acc[8][4];
#pragma unroll
  for (int i = 0; i < 8; ++i)
#pragma unroll
    for (int j = 0; j < 4; ++j) acc[i][j] = (f32x4)0.f;

  auto ldA = [&](unsigned char* ldsA, int qm) {
#pragma unroll
    for (int mi2 = 0; mi2 < 4; ++mi2) {
      ar[mi2][0] = *(const short8*)(ldsA + abase + qm * 8192 + mi2 * 2048 + s0);
      ar[mi2][1] = *(const short8*)(ldsA + abase + qm * 8192 + mi2 * 2048 + s1);
    }
  };
  auto ldB = [&](unsigned char* ldsB, int qn, short8 (&br)[2][2]) {
#pragma unroll
    for (int ni2 = 0; ni2 < 2; ++ni2) {
      br[ni2][0] = *(const short8*)(ldsB + bbase + qn * 4096 + ni2 * 2048 + s0);
      br[ni2][1] = *(const short8*)(ldsB + bbase + qn * 4096 + ni2 * 2048 + s1);
    }
  };

  stageA(A0, 0, 0); stageB(B0, 0, 0); stageA(A0, 1, 0); stageB(B0, 1, 0);
  stageA(A1, 0, 1); stageB(B1, 0, 1);
  asm volatile("s_waitcnt vmcnt(8)" ::: "memory");
  __builtin_amdgcn_s_barrier();

  for (int it = 0; it < niters - 1; ++it) {
    int t1 = 2 * it + 1, t2 = 2 * it + 2, t3 = 2 * it + 3;
    ldA(A0, 0); ldB(B0, 0, br0);
    stageA(A1, 1, t1);
    asm volatile("s_waitcnt vmcnt(6)" ::: "memory");
    PHASE_MID(); MMAQ(ar, br0, 0, 0); PHASE_END();
    ldB(B0, 1, br1);
    stageB(B1, 1, t1);
    PHASE_MID(); MMAQ(ar, br1, 0, 1); PHASE_END();
    ldA(A0, 1);
    stageA(A0, 0, t2);
    PHASE_MID(); MMAQ(ar, br0, 1, 0); PHASE_END();
    stageB(B0, 0, t2);
    asm volatile("s_waitcnt vmcnt(8)" ::: "memory");
    PHASE_MID(); MMAQ(ar, br1, 1, 1); PHASE_END();
    ldA(A1, 0); ldB(B1, 0, br0);
    stageA(A0, 1, t2);
    asm volatile("s_waitcnt vmcnt(6)" ::: "memory");
    PHASE_MID(); MMAQ(ar, br0, 0, 0); PHASE_END();
    ldB(B1, 1, br1);
    stageB(B0, 1, t2);
    PHASE_MID(); MMAQ(ar, br1, 0, 1); PHASE_END();
    ldA(A1, 1);
    if (t3 < NT) stageA(A1, 0, t3);
    PHASE_MID(); MMAQ(ar, br0, 1, 0); PHASE_END();
    if (t3 < NT) stageB(B1, 0, t3);
    asm volatile("s_waitcnt vmcnt(8)" ::: "memory");
    PHASE_MID(); MMAQ(ar, br1, 1, 1); PHASE_END();
  }
  {
    int t1 = NT - 1;
    ldA(A0, 0); ldB(B0, 0, br0);
    stageA(A1, 1, t1);
    asm volatile("s_waitcnt vmcnt(6)" ::: "memory");
    PHASE_MID(); MMAQ(ar, br0, 0, 0); PHASE_END();
    ldB(B0, 1, br1);
    stageB(B1, 1, t1);
    PHASE_MID(); MMAQ(ar, br1, 0, 1); PHASE_END();
    ldA(A0, 1);
    PHASE_MID(); MMAQ(ar, br0, 1, 0); PHASE_END();
    asm volatile("s_waitcnt vmcnt(4)" ::: "memory");
    PHASE_MID(); MMAQ(ar, br1, 1, 1); PHASE_END();
    ldA(A1, 0); ldB(B1, 0, br0);
    asm volatile("s_waitcnt vmcnt(2)" ::: "memory");
    PHASE_MID(); MMAQ(ar, br0, 0, 0); PHASE_END();
    ldB(B1, 1, br1);
    asm volatile("s_waitcnt vmcnt(0)" ::: "memory");
    PHASE_MID(); MMAQ(ar, br1, 0, 1); PHASE_END();
    ldA(A1, 1);
    PHASE_MID(); MMAQ(ar, br0, 1, 0); PHASE_END();
    PHASE_MID(); MMAQ(ar, br1, 1, 1); PHASE_END();
  }

  int rb = m0 + wm * 128 + (lane >> 4) * 4;
  int cb2 = n0 + wn * 64 + (lane & 15);
#pragma unroll
  for (int fm = 0; fm < 8; ++fm)
#pragma unroll
    for (int fn = 0; fn < 4; ++fn) {
      int c = cb2 + fn * 16;
      float bv = bias[c];
#pragma unroll
      for (int j = 0; j < 4; ++j) {
        int r = rb + fm * 16 + j;
        float val = acc[fm][fn][j] + bv;
        if (EPI == 2) {
          val = 0.5f * val * (1.0f + erff(val * 0.7071067811865476f));
          ((float*)C)[(size_t)r * N + c] = val;
        } else {
          ((unsigned short*)C)[(size_t)r * N + c] = f2bf(val);
        }
      }
    }
}

// ---- fused scores + softmax + weighted-sum (low-LDS, both branches) --------
__global__ __launch_bounds__(256) void k_attn2(
    const unsigned short* __restrict__ xln,   // [2*MROWS][EE]
    unsigned short* qky,                      // [2*BB][HH*EE]  in: qk, out: y
    const int* __restrict__ lastidx) {        // [2*BB]
  __shared__ __align__(16) unsigned short xs[10 * 1544];
  __shared__ float swp[4 * 256];
  __shared__ float scf[120];
  __shared__ float wsm[120];
  int b = blockIdx.x;                         // global batch (both branches)
  int t = threadIdx.x;
  const unsigned short* xg = xln + (size_t)b * SS * EE;
  unsigned short* qg = qky + (size_t)b * HH * EE;
#pragma unroll
  for (int j = 0; j < 8; ++j) {
    int idx = t + j * 256;
    if (idx < 1920) {
      int row = idx / 192, col = (idx - row * 192) * 8;
      *(short8*)(xs + row * 1544 + col) = *(const short8*)(xg + row * 1536 + col);
    }
  }
  __syncthreads();
  int w = t >> 6, lane = t & 63;
  {
    int hr = lane & 15; if (hr > 11) hr = 11;
    int sr = lane & 15; if (sr > 9) sr = 9;
    int kg = lane >> 4;
    f32x4 pacc = (f32x4)0.f;
#pragma unroll
    for (int kt = 0; kt < 12; ++kt) {
      int k0 = w * 384 + kt * 32 + kg * 8;
      short8 a  = *(const short8*)(qg + hr * 1536 + k0);
      short8 bf = *(const short8*)(xs + sr * 1544 + k0);
      pacc = __builtin_amdgcn_mfma_f32_16x16x32_bf16(a, bf, pacc, 0, 0, 0);
    }
    int prow = (lane >> 4) * 4, pcol = lane & 15;
#pragma unroll
    for (int j = 0; j < 4; ++j)
      swp[w * 256 + (prow + j) * 16 + pcol] = pacc[j];
  }
  __syncthreads();
  if (t < 120) {
    int h = t / 10, s = t - (t / 10) * 10;
    float v = swp[h * 16 + s] + swp[256 + h * 16 + s] +
              swp[512 + h * 16 + s] + swp[768 + h * 16 + s];
    scf[t] = v * 0.08838834764831845f;  // HD^-0.5
  }
  __syncthreads();
  int li = lastidx[b];
  if (t < 12) {
    float mx = -1e30f;
    for (int s = 0; s <= li; ++s) mx = fmaxf(mx, scf[t * 10 + s]);
    float sum = 0.f;
    for (int s = 0; s <= li; ++s) {
      float e = expf(scf[t * 10 + s] - mx);
      wsm[t * 10 + s] = e; sum += e;
    }
    float inv = 1.0f / sum;
    for (int s = 0; s <= li; ++s) wsm[t * 10 + s] *= inv;
  }
  __syncthreads();
  float wv[3][10];
#pragma unroll
  for (int hl = 0; hl < 3; ++hl)
#pragma unroll
    for (int s = 0; s < 10; ++s)
      wv[hl][s] = (s <= li) ? wsm[(3 * w + hl) * 10 + s] : 0.f;
#pragma unroll
  for (int pass = 0; pass < 12; ++pass) {
    int e0 = pass * 128 + lane * 2;
    float acc[3][2] = {};
    for (int s = 0; s <= li; ++s) {
      unsigned int x2 = *(const unsigned int*)(xs + s * 1544 + e0);
      float xlo = bf2f((unsigned short)(x2 & 0xffff));
      float xhi = bf2f((unsigned short)(x2 >> 16));
#pragma unroll
      for (int hl = 0; hl < 3; ++hl) {
        acc[hl][0] += wv[hl][s] * xlo;
        acc[hl][1] += wv[hl][s] * xhi;
      }
    }
#pragma unroll
    for (int hl = 0; hl < 3; ++hl) {
      unsigned int pk = (unsigned int)f2bf(acc[hl][0]) | ((unsigned int)f2bf(acc[hl][1]) << 16);
      *(unsigned int*)(qg + (3 * w + hl) * 1536 + e0) = pk;
    }
  }
}

extern "C" void kernel_launch(void* const* d_in, const int* in_sizes, int n_in,
                              void* d_out, int out_size, void* d_ws, size_t ws_size,
                              hipStream_t stream) {
  (void)in_sizes; (void)n_in; (void)out_size; (void)ws_size;
  const float* av  = (const float*)d_in[0];
  const float* bv  = (const float*)d_in[1];
  const void*  ma  = d_in[2];
  const void*  mb  = d_in[3];
  const float* qw  = (const float*)d_in[4];
  const float* qb  = (const float*)d_in[5];
  const float* kw  = (const float*)d_in[6];
  const float* kb  = (const float*)d_in[7];  (void)kb;  // softmax-invariant, dropped
  const float* vw  = (const float*)d_in[8];
  const float* vbs = (const float*)d_in[9];
  const float* ow  = (const float*)d_in[10];
  const float* ob  = (const float*)d_in[11];
  const float* fw  = (const float*)d_in[12];
  const float* fbs = (const float*)d_in[13];
  const float* lng = (const float*)d_in[14];
  const float* lnb = (const float*)d_in[15];

  unsigned char* ws = (unsigned char*)d_ws;
  size_t off = 0;
  auto alloc = [&](size_t bytes) {
    size_t r = off; off = (off + bytes + 255) & ~(size_t)255; return (void*)(ws + r);
  };
  int* flag             = (int*)alloc(4);
  float* pe             = (float*)alloc((size_t)SS * EE * 4);
  unsigned short* wt    = (unsigned short*)alloc((size_t)5 * EE * EE * 2);
  unsigned short* kwb   = (unsigned short*)alloc((size_t)EE * EE * 2);   // Wk bf16, [in][out]
  int* lastidx          = (int*)alloc((size_t)BB2 * 4);
  unsigned short* xln   = (unsigned short*)alloc((size_t)MROWS2 * EE * 2);     // 252 MB
  unsigned short* lastx = (unsigned short*)alloc((size_t)BB2 * EE * 2);        // 25 MB
  unsigned short* qbuf  = (unsigned short*)alloc((size_t)BB2 * EE * 2);        // 25 MB
  unsigned short* qky   = (unsigned short*)alloc((size_t)BB2 * HH * EE * 2);   // 302 MB
  unsigned short* ctx   = (unsigned short*)alloc((size_t)BB2 * EE * 2);        // 25 MB
  unsigned short* o1    = (unsigned short*)alloc((size_t)BB2 * EE * 2);        // 25 MB

  unsigned short* wt_q = wt;
  unsigned short* wt_v = wt + (size_t)2 * EE * EE;
  unsigned short* wt_o = wt + (size_t)3 * EE * EE;
  unsigned short* wt_f = wt + (size_t)4 * EE * EE;

  k_detect<<<1, 256, 0, stream>>>((const unsigned char*)ma, flag);
  k_pe<<<(SS * EE + 255) / 256, 256, 0, stream>>>(pe);
  k_trans<<<dim3(EE / 32, EE / 32, 5), dim3(32, 8), 0, stream>>>(qw, kw, vw, ow, fw, wt);
  k_cast<<<(EE * EE / 8 + 255) / 256, 256, 0, stream>>>(kw, kwb);
  k_lastidx<<<(BB2 + 255) / 256, 256, 0, stream>>>(ma, mb, flag, lastidx);

  // fused add-PE + LN, both branches: wave-per-row, 4 rows/block
  k_ln<<<MROWS2 / 4, 256, 0, stream>>>(av, bv, pe, lng, lnb, lastidx, xln, lastx);
  // Q projection: q = lastx @ Wq + qb   [8192 x 1536], 8-phase 256^2
  k_gemm256<0><<<(BB2 / 256) * (EE / 256), 512, 0, stream>>>(
      lastx, wt_q, qb, qbuf, BB2, EE, EE);
  // qk[b,h][e] = sum_d q[b,h,d] * Wk[e, h*128+d]; B[n=e][k=d] = kwb[e*EE + h*128+d]
  k_gemm_g<<<dim3(64 * 12, HH), 256, 0, stream>>>(
      qbuf, HDIM, EE, kwb, HDIM, EE, nullptr, 0, qky, EE, HH * EE, 64, 12, HDIM);
  // scores + softmax + weighted sum -> y (in place over qky), both branches
  k_attn2<<<BB2, 256, 0, stream>>>(xln, qky, lastidx);
  // ctx[b,hblk] = y[b,h] @ Wv[:,hblk] + bv  (per h: [8192x1536]@[1536x128])
  k_gemm_g<<<dim3(64 * 1, HH), 256, 0, stream>>>(
      qky, EE, HH * EE, wt_v, (size_t)0 + HDIM * EE, EE, vbs, HDIM,
      ctx, HDIM, EE, 64, 1, EE);
  // O projection: [8192 x 1536], 8-phase 256^2
  k_gemm256<0><<<(BB2 / 256) * (EE / 256), 512, 0, stream>>>(
      ctx, wt_o, ob, o1, BB2, EE, EE);
  // F projection + exact GELU -> f32 output (branch-major)
  k_gemm256<2><<<(BB2 / 256) * (EE / 256), 512, 0, stream>>>(
      o1, wt_f, fbs, d_out, BB2, EE, EE);
}